// Round 7
// baseline (1265.561 us; speedup 1.0000x reference)
//
#include <hip/hip_runtime.h>
#include <hip/hip_bf16.h>

typedef unsigned short u16;
typedef __bf16 bf16x8 __attribute__((ext_vector_type(8)));
typedef float f32x4 __attribute__((ext_vector_type(4)));

#define DEV __device__ __forceinline__

DEV u16 f2bf(float f) {
  __hip_bfloat16 h = __float2bfloat16(f);
  union { __hip_bfloat16 h; u16 u; } c; c.h = h; return c.u;
}
DEV float bf2f(u16 u) {
  unsigned int x = ((unsigned int)u) << 16; float f;
  __builtin_memcpy(&f, &x, 4); return f;
}
DEV float silu_f(float x) { return x / (1.f + __expf(-x)); }
DEV float gelu_f(float x) { return 0.5f * x * (1.f + erff(x * 0.70710678118654752f)); }

DEV void gl_lds16(const void* g, void* l) {
  __builtin_amdgcn_global_load_lds(
      (const __attribute__((address_space(1))) void*)g,
      (__attribute__((address_space(3))) void*)l, 16, 0, 0);
}

// ---------------------------------------------------------------------------
// 256x128 bf16 GEMM, BK=64, 512 threads = 8 waves (4M x 2N, per-wave 64x64),
// single-buffered 48KB LDS -> 3 blocks/CU capacity (24 waves/CU when grid
// allows; the R6 lesson: residency must not blow L2, so bigger blocks not
// more blocks). Inner loop identical to the R5 gemm128 (T2 XOR swizzle -> 0
// bank conflicts; T1 bijective XCD swizzle, x-major row-band order).
// EPI: 3 = +bias +res(f32) -> f32 out
//      4 = gelu(+bias) -> bf16 out
//      5 = dual: col<1024 -> bf16 (+bias) to outp ; col>=1024 -> bf16
//          silu(+bias2) to outp2 (both ld 1024)
// Requires: M%256==0, N%128==0, K%64==0, grid%8==0.
// ---------------------------------------------------------------------------
template<int EPI>
__global__ __launch_bounds__(512, 6)
void gemm_big(const u16* __restrict__ A, const u16* __restrict__ Bw,
              const float* __restrict__ bias, const float* __restrict__ bias2,
              const float* __restrict__ resp,
              void* __restrict__ outp, void* __restrict__ outp2,
              int M, int N, int K)
{
  __shared__ alignas(16) u16 As[256 * 64];   // 32KB
  __shared__ alignas(16) u16 Bs[128 * 64];   // 16KB

  const int t = threadIdx.x;
  const int w = t >> 6, l = t & 63;
  const int wm = w >> 1, wn = w & 1;          // 4M x 2N wave grid
  const int lr = l & 15, lq = l >> 4;
  const int ir = l >> 3, ik = l & 7;
  const int kkl = ik ^ ir;                    // T2 pre-swizzled global k-chunk

  // T1: bijective chunked XCD swizzle, x-major tile order (row-band per XCD)
  const int nwg = gridDim.x;
  int lin = blockIdx.x;
  lin = (lin & 7) * (nwg >> 3) + (lin >> 3);
  const int nbx = N >> 7;
  const int by = lin / nbx, bx = lin - by * nbx;
  const int brow = by << 8, bcol = bx << 7;

  // staging: wave w covers rows {s*64 + w*8 + ir}, 16B chunk kkl
  const u16* gA = A + (size_t)(brow + w * 8 + ir) * K + kkl * 8;
  const u16* gB = Bw + (size_t)(bcol + w * 8 + ir) * K + kkl * 8;

  f32x4 acc[4][4] = {};
  const int nt = K >> 6;

  for (int kt = 0; kt < nt; ++kt) {
#pragma unroll
    for (int s = 0; s < 4; ++s)
      gl_lds16(gA + (size_t)(s * 64) * K, &As[(s * 64 + w * 8) * 64]);
#pragma unroll
    for (int s = 0; s < 2; ++s)
      gl_lds16(gB + (size_t)(s * 64) * K, &Bs[(s * 64 + w * 8) * 64]);
    gA += 64; gB += 64;
    __syncthreads();                   // drain vm+lgkm, barrier
#pragma unroll
    for (int ks = 0; ks < 2; ++ks) {
      bf16x8 af[4], bf[4];
#pragma unroll
      for (int mi = 0; mi < 4; ++mi) {
        const int ro = wm * 64 + mi * 16 + lr;
        const int ck = (ks * 4 + lq) ^ (ro & 7);
        af[mi] = *(const bf16x8*)&As[ro * 64 + ck * 8];
      }
#pragma unroll
      for (int ni = 0; ni < 4; ++ni) {
        const int ro = wn * 64 + ni * 16 + lr;
        const int ck = (ks * 4 + lq) ^ (ro & 7);
        bf[ni] = *(const bf16x8*)&Bs[ro * 64 + ck * 8];
      }
#pragma unroll
      for (int mi = 0; mi < 4; ++mi)
#pragma unroll
        for (int ni = 0; ni < 4; ++ni)
          acc[mi][ni] = __builtin_amdgcn_mfma_f32_16x16x32_bf16(af[mi], bf[ni], acc[mi][ni], 0, 0, 0);
    }
    __syncthreads();                   // reads done before next overwrite
  }

  // epilogue: row = brow + wm*64 + mi*16 + lq*4 + r ; col = bcol + wn*64 + ni*16 + lr
#pragma unroll
  for (int ni = 0; ni < 4; ++ni) {
    const int col = bcol + wn * 64 + ni * 16 + lr;
    float bv = 0.f;
    if (EPI == 3 || EPI == 4) bv = bias[col];
    if (EPI == 5) bv = (col < 1024) ? bias[col] : bias2[col - 1024];
#pragma unroll
    for (int mi = 0; mi < 4; ++mi) {
      const int row0 = brow + wm * 64 + mi * 16 + lq * 4;
#pragma unroll
      for (int r = 0; r < 4; ++r) {
        const int row = row0 + r;
        const float raw = acc[mi][ni][r];
        if (EPI == 3) {
          const size_t idx = (size_t)row * N + col;
          ((float*)outp)[idx] = raw + bv + resp[idx];
        } else if (EPI == 4) {
          ((u16*)outp)[(size_t)row * N + col] = f2bf(gelu_f(raw + bv));
        } else {
          if (col < 1024) ((u16*)outp)[(size_t)row * 1024 + col] = f2bf(raw + bv);
          else ((u16*)outp2)[(size_t)row * 1024 + (col - 1024)] = f2bf(silu_f(raw + bv));
        }
      }
    }
  }
}

// ---------------------------------------------------------------------------
// Small-shape bf16 GEMM. 128x128 tile, BK=32, 4 waves, 2-phase dbuf.
// Kst = row stride of A/B (elements); K = k-length iterated by THIS block.
// blockIdx.z = split-K part (A,B offset by part*K; outp by part*M*N).
// EPI: 0 = +bias -> f32 ; 2 = (*mul) -> bf16.
// ---------------------------------------------------------------------------
template<int EPI>
__global__ __launch_bounds__(256)
void gemm_bt(const u16* __restrict__ A, const u16* __restrict__ Bw,
             const float* __restrict__ bias, const u16* __restrict__ mulp,
             void* __restrict__ outp, int M, int N, int K, int Kst)
{
  __shared__ u16 As[2][128 * 32];
  __shared__ u16 Bs[2][128 * 32];
  const int t = threadIdx.x;
  const int w = t >> 6, l = t & 63;
  const int wr = w >> 1, wc = w & 1;
  const int brow = blockIdx.y << 7;
  const int bcol = blockIdx.x << 7;
  const int part = blockIdx.z;
  A += (size_t)part * K;
  Bw += (size_t)part * K;
  float* outf = (float*)outp + (size_t)part * M * N;

  const u16* gA0 = A + (size_t)(brow + (t >> 2)) * Kst + ((t & 3) << 3);
  const u16* gA1 = gA0 + (size_t)64 * Kst;
  int bn0 = bcol + (t >> 2);      if (bn0 > N - 1) bn0 = N - 1;
  int bn1 = bcol + 64 + (t >> 2); if (bn1 > N - 1) bn1 = N - 1;
  const u16* gB0 = Bw + (size_t)bn0 * Kst + ((t & 3) << 3);
  const u16* gB1 = Bw + (size_t)bn1 * Kst + ((t & 3) << 3);
  const int woff = w << 9;

  auto stage = [&](int b) {
    gl_lds16(gA0, &As[b][woff]);        gl_lds16(gA1, &As[b][2048 + woff]);
    gl_lds16(gB0, &Bs[b][woff]);        gl_lds16(gB1, &Bs[b][2048 + woff]);
    gA0 += 32; gA1 += 32; gB0 += 32; gB1 += 32;
  };

  f32x4 acc[4][4] = {};
  const int lr = l & 15, lk = (l >> 4) << 3;
  const int nt = K >> 5;

  stage(0);
  __syncthreads();
  int cur = 0;
  for (int kt = 0; kt < nt; ++kt) {
    if (kt + 1 < nt) stage(cur ^ 1);
    bf16x8 af[4], bfr[4];
#pragma unroll
    for (int i = 0; i < 4; ++i)
      af[i] = *(const bf16x8*)&As[cur][(wr * 64 + i * 16 + lr) * 32 + lk];
#pragma unroll
    for (int j = 0; j < 4; ++j)
      bfr[j] = *(const bf16x8*)&Bs[cur][(wc * 64 + j * 16 + lr) * 32 + lk];
#pragma unroll
    for (int i = 0; i < 4; ++i)
#pragma unroll
      for (int j = 0; j < 4; ++j)
        acc[i][j] = __builtin_amdgcn_mfma_f32_16x16x32_bf16(af[i], bfr[j], acc[i][j], 0, 0, 0);
    __syncthreads();
    cur ^= 1;
  }

  const int lq = l >> 4;
#pragma unroll
  for (int j = 0; j < 4; ++j) {
    const int col = bcol + wc * 64 + j * 16 + lr;
    if (col >= N) continue;
    const float bv = (EPI == 0 && bias) ? bias[col] : 0.f;
#pragma unroll
    for (int i = 0; i < 4; ++i) {
      const int row0 = brow + wr * 64 + i * 16 + lq * 4;
#pragma unroll
      for (int r = 0; r < 4; ++r) {
        const size_t idx = (size_t)(row0 + r) * N + col;
        const float raw = acc[i][j][r];
        if (EPI == 0) outf[idx] = raw + bv;
        else          ((u16*)outp)[idx] = f2bf(raw * bf2f(mulp[idx]));
      }
    }
  }
}

// ---------------------------------------------------------------------------
// LayerNorm over last dim (1024), fp32 in -> bf16 out. One block per row.
// ---------------------------------------------------------------------------
__global__ __launch_bounds__(256)
void ln_bf16(const float* __restrict__ x, const float* __restrict__ g,
             const float* __restrict__ b, u16* __restrict__ out)
{
  const int row = blockIdx.x;
  const int t = threadIdx.x;
  const float4 v = ((const float4*)(x + (size_t)row * 1024))[t];
  float s = v.x + v.y + v.z + v.w;
  float sq = v.x * v.x + v.y * v.y + v.z * v.z + v.w * v.w;
#pragma unroll
  for (int o = 32; o; o >>= 1) { s += __shfl_xor(s, o); sq += __shfl_xor(sq, o); }
  __shared__ float ls[8];
  const int w = t >> 6, l = t & 63;
  if (l == 0) { ls[w] = s; ls[4 + w] = sq; }
  __syncthreads();
  s = ls[0] + ls[1] + ls[2] + ls[3];
  sq = ls[4] + ls[5] + ls[6] + ls[7];
  const float mean = s * (1.f / 1024.f);
  const float var = sq * (1.f / 1024.f) - mean * mean;
  const float rs = rsqrtf(var + 1e-5f);
  const float4 gg = ((const float4*)g)[t];
  const float4 bb = ((const float4*)b)[t];
  ushort4 o;
  o.x = f2bf((v.x - mean) * rs * gg.x + bb.x);
  o.y = f2bf((v.y - mean) * rs * gg.y + bb.y);
  o.z = f2bf((v.z - mean) * rs * gg.z + bb.z);
  o.w = f2bf((v.w - mean) * rs * gg.w + bb.w);
  ((ushort4*)(out + (size_t)row * 1024))[t] = o;
}

// ---------------------------------------------------------------------------
// Depthwise conv1d (k=3, pad=1) + SiLU. x1 bf16 [B,S,D] -> xc bf16.
// ---------------------------------------------------------------------------
__global__ __launch_bounds__(256)
void conv_silu(const u16* __restrict__ x1, const float* __restrict__ cwT,
               u16* __restrict__ xc, int S)
{
  const size_t gid = (size_t)blockIdx.x * 256 + threadIdx.x;
  const int dq = (int)(gid & 255);
  const size_t tok = gid >> 8;
  const int s = (int)(tok % (size_t)S);
  ushort4 zz; zz.x = 0; zz.y = 0; zz.z = 0; zz.w = 0;
  const ushort4* base = (const ushort4*)x1 + tok * 256;
  const ushort4 xm = (s > 0) ? base[dq - 256] : zz;
  const ushort4 x0 = base[dq];
  const ushort4 xp = (s < S - 1) ? base[dq + 256] : zz;
  const float4 w0 = ((const float4*)cwT)[dq];
  const float4 w1 = ((const float4*)(cwT + 1024))[dq];
  const float4 w2 = ((const float4*)(cwT + 2048))[dq];
  ushort4 o;
  o.x = f2bf(silu_f(w0.x * bf2f(xm.x) + w1.x * bf2f(x0.x) + w2.x * bf2f(xp.x)));
  o.y = f2bf(silu_f(w0.y * bf2f(xm.y) + w1.y * bf2f(x0.y) + w2.y * bf2f(xp.y)));
  o.z = f2bf(silu_f(w0.z * bf2f(xm.z) + w1.z * bf2f(x0.z) + w2.z * bf2f(xp.z)));
  o.w = f2bf(silu_f(w0.w * bf2f(xm.w) + w1.w * bf2f(x0.w) + w2.w * bf2f(xp.w)));
  ((ushort4*)xc)[gid] = o;
}

// ---------------------------------------------------------------------------
// SSM scan: h_t = A h_{t-1} + U_t (64-dim), U given as 4 split-K partials
// (stride PS elems). Overlapping chunks: 32 warm-up steps from h=0 then 32
// emitted (||A^32|| ~ 2e-13 -> exact at fp32).
// ---------------------------------------------------------------------------
__global__ __launch_bounds__(64)
void ssm_scan(const float* __restrict__ Amat, const float* __restrict__ U,
              u16* __restrict__ H, int S, size_t PS)
{
  const int b = blockIdx.y;
  const int c = blockIdx.x;
  const int j = threadIdx.x;
  const int s0 = c * 32;
  const int tstart = (s0 >= 32) ? (s0 - 32) : 0;
  float4 Ar[16];
#pragma unroll
  for (int q = 0; q < 16; ++q) Ar[q] = ((const float4*)(Amat + j * 64))[q];
  __shared__ float hb[64];
  float h = 0.f;
  const float* Ub = U + (size_t)b * S * 64;
  u16* Hb = H + (size_t)b * S * 64;
  for (int t = tstart; t < s0 + 32; ++t) {
    hb[j] = h;
    __syncthreads();
    const size_t idx = (size_t)t * 64 + j;
    float acc0 = Ub[idx] + Ub[PS + idx] + Ub[2 * PS + idx] + Ub[3 * PS + idx];
#pragma unroll
    for (int q = 0; q < 16; ++q) {
      const float4 hv = *(const float4*)&hb[q * 4];
      acc0 += Ar[q].x * hv.x + Ar[q].y * hv.y + Ar[q].z * hv.z + Ar[q].w * hv.w;
    }
    __syncthreads();
    h = acc0;
    if (t >= s0) Hb[idx] = f2bf(h);
  }
}

// ---------------------------------------------------------------------------
// Combined fp32 -> bf16 weight convert: 7 source segments into one contiguous
// dst region (single launch replaces 7).
// ---------------------------------------------------------------------------
struct CvtArgs {
  const float* src[7];
  unsigned beg4[8];   // segment boundaries in float4 units
};

__global__ __launch_bounds__(256)
void cvt_all(CvtArgs a, u16* __restrict__ dst)
{
  const unsigned i = blockIdx.x * 256 + threadIdx.x;
  if (i >= a.beg4[7]) return;
  int s = 0;
#pragma unroll
  for (int k = 1; k < 7; ++k) if (i >= a.beg4[k]) s = k;
  const float4 v = ((const float4*)a.src[s])[i - a.beg4[s]];
  ushort4 o;
  o.x = f2bf(v.x); o.y = f2bf(v.y); o.z = f2bf(v.z); o.w = f2bf(v.w);
  ((ushort4*)dst)[i] = o;
}

// conv_w [D,1,3] -> cwT [3][D] fp32
__global__ __launch_bounds__(256)
void cvt_convw(const float* __restrict__ cw, float* __restrict__ cwT)
{
  const int d = blockIdx.x * 256 + threadIdx.x;
  if (d < 1024) {
    cwT[d]        = cw[d * 3 + 0];
    cwT[1024 + d] = cw[d * 3 + 1];
    cwT[2048 + d] = cw[d * 3 + 2];
  }
}

extern "C" void kernel_launch(void* const* d_in, const int* in_sizes, int n_in,
                              void* d_out, int out_size, void* d_ws, size_t ws_size,
                              hipStream_t stream)
{
  (void)in_sizes; (void)n_in; (void)out_size; (void)ws_size;
  const float* x     = (const float*)d_in[0];
  const float* w1_w  = (const float*)d_in[1];
  const float* w1_b  = (const float*)d_in[2];
  const float* v1_w  = (const float*)d_in[3];
  const float* v1_b  = (const float*)d_in[4];
  const float* w2_w  = (const float*)d_in[5];
  const float* w2_b  = (const float*)d_in[6];
  const float* convw = (const float*)d_in[7];
  const float* Amat  = (const float*)d_in[8];
  const float* Bm    = (const float*)d_in[9];
  const float* Cm    = (const float*)d_in[10];
  const float* ln1_g = (const float*)d_in[11];
  const float* ln1_b = (const float*)d_in[12];
  const float* ln2_g = (const float*)d_in[13];
  const float* ln2_b = (const float*)d_in[14];
  const float* ff1_w = (const float*)d_in[15];
  const float* ff1_b = (const float*)d_in[16];
  const float* ff2_w = (const float*)d_in[17];
  const float* ff2_b = (const float*)d_in[18];

  const int S = 2048, D = 1024, Dff = 2048, NS = 64, BATCH = 4;
  const int NT = BATCH * S; // 8192 tokens

  char* ws = (char*)d_ws;
  size_t off = 0;
  auto alc = [&](size_t bytes) -> void* {
    void* p = ws + off; off += (bytes + 255) & ~(size_t)255; return p;
  };
  u16*   wb1  = (u16*)alc((size_t)D * D * 2);   // w1 || v1 contiguous -> [2048,1024]
  u16*   wv1  = (u16*)alc((size_t)D * D * 2);
  u16*   ww2  = (u16*)alc((size_t)D * D * 2);
  u16*   wf1  = (u16*)alc((size_t)Dff * D * 2);
  u16*   wf2  = (u16*)alc((size_t)D * Dff * 2);
  u16*   wBm  = (u16*)alc((size_t)NS * D * 2);
  u16*   wCm  = (u16*)alc((size_t)D * NS * 2);
  float* cwT  = (float*)alc((size_t)3 * D * 4);
  u16*   h1g  = (u16*)alc((size_t)NT * D * 2);   // h1 (ln1 out), later g
  u16*   vbuf = (u16*)alc((size_t)NT * D * 2);   // v = silu(h@v1^T)
  float* Xb   = (float*)alc((size_t)NT * D * 4); // x1 (bf16 alias), later x2 f32
  u16*   xch2 = (u16*)alc((size_t)NT * D * 2);   // xc, later h2
  float* Ubuf = (float*)alc((size_t)4 * NT * NS * 4); // 4 split-K partials
  u16*   Hbuf = (u16*)alc((size_t)NT * NS * 2);
  u16*   f1b  = (u16*)alc((size_t)NT * Dff * 2);
  u16*   x1b  = (u16*)Xb;                        // x1 bf16 aliases Xb (dead before x2)

  const dim3 blk(256);

  // single combined weight conversion (dst = contiguous wb1..wCm region)
  {
    CvtArgs a;
    const unsigned q = (unsigned)(D * D / 4);      // 262144
    const unsigned qf = (unsigned)(Dff * D / 4);   // 524288
    const unsigned qs = (unsigned)(NS * D / 4);    // 16384
    a.src[0] = w1_w;  a.src[1] = v1_w;  a.src[2] = w2_w;
    a.src[3] = ff1_w; a.src[4] = ff2_w; a.src[5] = Bm; a.src[6] = Cm;
    a.beg4[0] = 0;
    a.beg4[1] = q;          a.beg4[2] = 2 * q;      a.beg4[3] = 3 * q;
    a.beg4[4] = 3 * q + qf; a.beg4[5] = 3 * q + 2 * qf;
    a.beg4[6] = 3 * q + 2 * qf + qs;
    a.beg4[7] = 3 * q + 2 * qf + 2 * qs;
    hipLaunchKernelGGL(cvt_all, dim3((a.beg4[7] + 255) / 256), blk, 0, stream, a, wb1);
  }
  hipLaunchKernelGGL(cvt_convw, dim3(4), blk, 0, stream, convw, cwT);

  // h1 = LN1(x)
  hipLaunchKernelGGL(ln_bf16, dim3(NT), blk, 0, stream, x, ln1_g, ln1_b, h1g);
  // fused: x1 = h1@w1^T + b1 (bf16 -> x1b) ; v = silu(h1@v1^T + b) (bf16 -> vbuf)
  hipLaunchKernelGGL((gemm_big<5>), dim3((NT / 256) * (2 * D / 128)), dim3(512), 0, stream,
                     h1g, wb1, w1_b, v1_b, (const float*)nullptr,
                     (void*)x1b, (void*)vbuf, NT, 2 * D, D);
  // xc = silu(dwconv(x1))  (bf16)
  hipLaunchKernelGGL(conv_silu, dim3(NT), blk, 0, stream, x1b, cwT, xch2, S);
  // U partials = xc @ Bm^T  (fp32, N=64, split-K=4 -> grid (1,64,4))
  hipLaunchKernelGGL((gemm_bt<0>), dim3(1, NT / 128, 4), blk, 0, stream,
                     xch2, wBm, (const float*)nullptr, (const u16*)nullptr,
                     (void*)Ubuf, NT, NS, D / 4, D);
  // H = scan(A, sum of U partials)  (bf16)
  hipLaunchKernelGGL(ssm_scan, dim3(S / 32, BATCH), dim3(64), 0, stream,
                     Amat, Ubuf, Hbuf, S, (size_t)NT * NS);
  // g = (H @ Cm^T) * v  (bf16) -> reuse h1 region
  hipLaunchKernelGGL((gemm_bt<2>), dim3(D / 128, NT / 128, 1), blk, 0, stream,
                     Hbuf, wCm, (const float*)nullptr, vbuf,
                     (void*)h1g, NT, D, NS, NS);
  // x2 = g @ w2^T + b2 + x  (fp32 -> Xb)
  hipLaunchKernelGGL((gemm_big<3>), dim3((NT / 256) * (D / 128)), dim3(512), 0, stream,
                     h1g, ww2, w2_b, (const float*)nullptr, x,
                     (void*)Xb, (void*)nullptr, NT, D, D);
  // h2 = LN2(x2)  (bf16) -> reuse xc region
  hipLaunchKernelGGL(ln_bf16, dim3(NT), blk, 0, stream, Xb, ln2_g, ln2_b, xch2);
  // f1 = gelu(h2 @ ff1^T + b)  (bf16)
  hipLaunchKernelGGL((gemm_big<4>), dim3((NT / 256) * (Dff / 128)), dim3(512), 0, stream,
                     xch2, wf1, ff1_b, (const float*)nullptr, (const float*)nullptr,
                     (void*)f1b, (void*)nullptr, NT, Dff, D);
  // out = f1 @ ff2^T + b + x2  (fp32)
  hipLaunchKernelGGL((gemm_big<3>), dim3((NT / 256) * (D / 128)), dim3(512), 0, stream,
                     f1b, wf2, ff2_b, (const float*)nullptr, Xb,
                     d_out, (void*)nullptr, NT, D, Dff);
}

// Round 8
// 290.468 us; speedup vs baseline: 4.3570x; 4.3570x over previous
//
#include <hip/hip_runtime.h>
#include <hip/hip_bf16.h>

typedef unsigned short u16;
typedef __bf16 bf16x8 __attribute__((ext_vector_type(8)));
typedef float f32x4 __attribute__((ext_vector_type(4)));

#define DEV __device__ __forceinline__

DEV u16 f2bf(float f) {
  __hip_bfloat16 h = __float2bfloat16(f);
  union { __hip_bfloat16 h; u16 u; } c; c.h = h; return c.u;
}
DEV float bf2f(u16 u) {
  unsigned int x = ((unsigned int)u) << 16; float f;
  __builtin_memcpy(&f, &x, 4); return f;
}
DEV float silu_f(float x) { return x / (1.f + __expf(-x)); }
DEV float gelu_f(float x) { return 0.5f * x * (1.f + erff(x * 0.70710678118654752f)); }

DEV void gl_lds16(const void* g, void* l) {
  __builtin_amdgcn_global_load_lds(
      (const __attribute__((address_space(1))) void*)g,
      (__attribute__((address_space(3))) void*)l, 16, 0, 0);
}

// ---------------------------------------------------------------------------
// 128x128 bf16 GEMM, BK=64, 4 waves (2x2 of 64x64), single-buffered 32KB LDS.
// __launch_bounds__(256,4): VGPR cap 128 -> NO SPILL (kernel needs ~90; the
// R6/R7 regressions were accumulator spills from tighter caps: VGPR 48/40,
// WRITE_SIZE 210-918MB of scratch traffic). 4 blocks/CU capacity
// (4 x 32KB = 128KB LDS); cross-block TLP hides the per-K-step stage drain.
// T2 XOR swizzle (0 bank conflicts, verified), T1 bijective XCD swizzle.
// EPI: 3 = +bias +res(f32) -> f32 out
//      4 = gelu(+bias) -> bf16 out
//      5 = dual: col<1024 -> bf16 (+bias) to outp ; col>=1024 -> bf16
//          silu(+bias2) to outp2 (both ld 1024)
// Requires: M%128==0, N%128==0, K%64==0, grid%8==0.
// ---------------------------------------------------------------------------
template<int EPI>
__global__ __launch_bounds__(256, 4)
void gemm128(const u16* __restrict__ A, const u16* __restrict__ Bw,
             const float* __restrict__ bias, const float* __restrict__ bias2,
             const float* __restrict__ resp,
             void* __restrict__ outp, void* __restrict__ outp2,
             int M, int N, int K)
{
  __shared__ alignas(16) u16 As[128 * 64];
  __shared__ alignas(16) u16 Bs[128 * 64];

  const int t = threadIdx.x;
  const int w = t >> 6, l = t & 63;
  const int wm = w >> 1, wn = w & 1;
  const int lr = l & 15, lq = l >> 4;
  const int ir = l >> 3, ik = l & 7;
  const int kkl = ik ^ ir;             // T2 pre-swizzled global k-chunk

  // T1: bijective chunked XCD swizzle, x-major tile order (row-band per XCD)
  const int nwg = gridDim.x;
  int lin = blockIdx.x;
  lin = (lin & 7) * (nwg >> 3) + (lin >> 3);
  const int nbx = N >> 7;
  const int by = lin / nbx, bx = lin - by * nbx;
  const int brow = by << 7, bcol = bx << 7;

  // staging: wave w, sub s covers rows s*32 + w*8 + ir, chunk kkl (16B)
  const u16* gA = A + (size_t)(brow + w * 8 + ir) * K + kkl * 8;
  const u16* gB = Bw + (size_t)(bcol + w * 8 + ir) * K + kkl * 8;

  f32x4 acc[4][4] = {};
  const int nt = K >> 6;

  for (int kt = 0; kt < nt; ++kt) {
#pragma unroll
    for (int s = 0; s < 4; ++s) {
      gl_lds16(gA + (size_t)(s * 32) * K, &As[(s * 32 + w * 8) * 64]);
      gl_lds16(gB + (size_t)(s * 32) * K, &Bs[(s * 32 + w * 8) * 64]);
    }
    gA += 64; gB += 64;
    __syncthreads();                   // drain vm+lgkm, barrier
#pragma unroll
    for (int ks = 0; ks < 2; ++ks) {
      bf16x8 af[4], bf[4];
#pragma unroll
      for (int mi = 0; mi < 4; ++mi) {
        const int ro = wm * 64 + mi * 16 + lr;
        const int ck = (ks * 4 + lq) ^ (ro & 7);
        af[mi] = *(const bf16x8*)&As[ro * 64 + ck * 8];
      }
#pragma unroll
      for (int ni = 0; ni < 4; ++ni) {
        const int ro = wn * 64 + ni * 16 + lr;
        const int ck = (ks * 4 + lq) ^ (ro & 7);
        bf[ni] = *(const bf16x8*)&Bs[ro * 64 + ck * 8];
      }
#pragma unroll
      for (int mi = 0; mi < 4; ++mi)
#pragma unroll
        for (int ni = 0; ni < 4; ++ni)
          acc[mi][ni] = __builtin_amdgcn_mfma_f32_16x16x32_bf16(af[mi], bf[ni], acc[mi][ni], 0, 0, 0);
    }
    __syncthreads();                   // reads done before next overwrite
  }

  // epilogue: row = brow + wm*64 + mi*16 + lq*4 + r ; col = bcol + wn*64 + ni*16 + lr
#pragma unroll
  for (int ni = 0; ni < 4; ++ni) {
    const int col = bcol + wn * 64 + ni * 16 + lr;
    float bv = 0.f;
    if (EPI == 3 || EPI == 4) bv = bias[col];
    if (EPI == 5) bv = (col < 1024) ? bias[col] : bias2[col - 1024];
#pragma unroll
    for (int mi = 0; mi < 4; ++mi) {
      const int row0 = brow + wm * 64 + mi * 16 + lq * 4;
#pragma unroll
      for (int r = 0; r < 4; ++r) {
        const int row = row0 + r;
        const float raw = acc[mi][ni][r];
        if (EPI == 3) {
          const size_t idx = (size_t)row * N + col;
          ((float*)outp)[idx] = raw + bv + resp[idx];
        } else if (EPI == 4) {
          ((u16*)outp)[(size_t)row * N + col] = f2bf(gelu_f(raw + bv));
        } else {
          if (col < 1024) ((u16*)outp)[(size_t)row * 1024 + col] = f2bf(raw + bv);
          else ((u16*)outp2)[(size_t)row * 1024 + (col - 1024)] = f2bf(silu_f(raw + bv));
        }
      }
    }
  }
}

// ---------------------------------------------------------------------------
// Small-shape bf16 GEMM. 128x128 tile, BK=32, 4 waves, 2-phase dbuf.
// Kst = row stride of A/B (elements); K = k-length iterated by THIS block.
// blockIdx.z = split-K part (A,B offset by part*K; outp by part*M*N).
// EPI: 0 = +bias -> f32 ; 2 = (*mul) -> bf16.
// ---------------------------------------------------------------------------
template<int EPI>
__global__ __launch_bounds__(256)
void gemm_bt(const u16* __restrict__ A, const u16* __restrict__ Bw,
             const float* __restrict__ bias, const u16* __restrict__ mulp,
             void* __restrict__ outp, int M, int N, int K, int Kst)
{
  __shared__ u16 As[2][128 * 32];
  __shared__ u16 Bs[2][128 * 32];
  const int t = threadIdx.x;
  const int w = t >> 6, l = t & 63;
  const int wr = w >> 1, wc = w & 1;
  const int brow = blockIdx.y << 7;
  const int bcol = blockIdx.x << 7;
  const int part = blockIdx.z;
  A += (size_t)part * K;
  Bw += (size_t)part * K;
  float* outf = (float*)outp + (size_t)part * M * N;

  const u16* gA0 = A + (size_t)(brow + (t >> 2)) * Kst + ((t & 3) << 3);
  const u16* gA1 = gA0 + (size_t)64 * Kst;
  int bn0 = bcol + (t >> 2);      if (bn0 > N - 1) bn0 = N - 1;
  int bn1 = bcol + 64 + (t >> 2); if (bn1 > N - 1) bn1 = N - 1;
  const u16* gB0 = Bw + (size_t)bn0 * Kst + ((t & 3) << 3);
  const u16* gB1 = Bw + (size_t)bn1 * Kst + ((t & 3) << 3);
  const int woff = w << 9;

  auto stage = [&](int b) {
    gl_lds16(gA0, &As[b][woff]);        gl_lds16(gA1, &As[b][2048 + woff]);
    gl_lds16(gB0, &Bs[b][woff]);        gl_lds16(gB1, &Bs[b][2048 + woff]);
    gA0 += 32; gA1 += 32; gB0 += 32; gB1 += 32;
  };

  f32x4 acc[4][4] = {};
  const int lr = l & 15, lk = (l >> 4) << 3;
  const int nt = K >> 5;

  stage(0);
  __syncthreads();
  int cur = 0;
  for (int kt = 0; kt < nt; ++kt) {
    if (kt + 1 < nt) stage(cur ^ 1);
    bf16x8 af[4], bfr[4];
#pragma unroll
    for (int i = 0; i < 4; ++i)
      af[i] = *(const bf16x8*)&As[cur][(wr * 64 + i * 16 + lr) * 32 + lk];
#pragma unroll
    for (int j = 0; j < 4; ++j)
      bfr[j] = *(const bf16x8*)&Bs[cur][(wc * 64 + j * 16 + lr) * 32 + lk];
#pragma unroll
    for (int i = 0; i < 4; ++i)
#pragma unroll
      for (int j = 0; j < 4; ++j)
        acc[i][j] = __builtin_amdgcn_mfma_f32_16x16x32_bf16(af[i], bfr[j], acc[i][j], 0, 0, 0);
    __syncthreads();
    cur ^= 1;
  }

  const int lq = l >> 4;
#pragma unroll
  for (int j = 0; j < 4; ++j) {
    const int col = bcol + wc * 64 + j * 16 + lr;
    if (col >= N) continue;
    const float bv = (EPI == 0 && bias) ? bias[col] : 0.f;
#pragma unroll
    for (int i = 0; i < 4; ++i) {
      const int row0 = brow + wr * 64 + i * 16 + lq * 4;
#pragma unroll
      for (int r = 0; r < 4; ++r) {
        const size_t idx = (size_t)(row0 + r) * N + col;
        const float raw = acc[i][j][r];
        if (EPI == 0) outf[idx] = raw + bv;
        else          ((u16*)outp)[idx] = f2bf(raw * bf2f(mulp[idx]));
      }
    }
  }
}

// ---------------------------------------------------------------------------
// LayerNorm over last dim (1024), fp32 in -> bf16 out. One block per row.
// ---------------------------------------------------------------------------
__global__ __launch_bounds__(256)
void ln_bf16(const float* __restrict__ x, const float* __restrict__ g,
             const float* __restrict__ b, u16* __restrict__ out)
{
  const int row = blockIdx.x;
  const int t = threadIdx.x;
  const float4 v = ((const float4*)(x + (size_t)row * 1024))[t];
  float s = v.x + v.y + v.z + v.w;
  float sq = v.x * v.x + v.y * v.y + v.z * v.z + v.w * v.w;
#pragma unroll
  for (int o = 32; o; o >>= 1) { s += __shfl_xor(s, o); sq += __shfl_xor(sq, o); }
  __shared__ float ls[8];
  const int w = t >> 6, l = t & 63;
  if (l == 0) { ls[w] = s; ls[4 + w] = sq; }
  __syncthreads();
  s = ls[0] + ls[1] + ls[2] + ls[3];
  sq = ls[4] + ls[5] + ls[6] + ls[7];
  const float mean = s * (1.f / 1024.f);
  const float var = sq * (1.f / 1024.f) - mean * mean;
  const float rs = rsqrtf(var + 1e-5f);
  const float4 gg = ((const float4*)g)[t];
  const float4 bb = ((const float4*)b)[t];
  ushort4 o;
  o.x = f2bf((v.x - mean) * rs * gg.x + bb.x);
  o.y = f2bf((v.y - mean) * rs * gg.y + bb.y);
  o.z = f2bf((v.z - mean) * rs * gg.z + bb.z);
  o.w = f2bf((v.w - mean) * rs * gg.w + bb.w);
  ((ushort4*)(out + (size_t)row * 1024))[t] = o;
}

// ---------------------------------------------------------------------------
// Depthwise conv1d (k=3, pad=1) + SiLU. x1 bf16 [B,S,D] -> xc bf16.
// ---------------------------------------------------------------------------
__global__ __launch_bounds__(256)
void conv_silu(const u16* __restrict__ x1, const float* __restrict__ cwT,
               u16* __restrict__ xc, int S)
{
  const size_t gid = (size_t)blockIdx.x * 256 + threadIdx.x;
  const int dq = (int)(gid & 255);
  const size_t tok = gid >> 8;
  const int s = (int)(tok % (size_t)S);
  ushort4 zz; zz.x = 0; zz.y = 0; zz.z = 0; zz.w = 0;
  const ushort4* base = (const ushort4*)x1 + tok * 256;
  const ushort4 xm = (s > 0) ? base[dq - 256] : zz;
  const ushort4 x0 = base[dq];
  const ushort4 xp = (s < S - 1) ? base[dq + 256] : zz;
  const float4 w0 = ((const float4*)cwT)[dq];
  const float4 w1 = ((const float4*)(cwT + 1024))[dq];
  const float4 w2 = ((const float4*)(cwT + 2048))[dq];
  ushort4 o;
  o.x = f2bf(silu_f(w0.x * bf2f(xm.x) + w1.x * bf2f(x0.x) + w2.x * bf2f(xp.x)));
  o.y = f2bf(silu_f(w0.y * bf2f(xm.y) + w1.y * bf2f(x0.y) + w2.y * bf2f(xp.y)));
  o.z = f2bf(silu_f(w0.z * bf2f(xm.z) + w1.z * bf2f(x0.z) + w2.z * bf2f(xp.z)));
  o.w = f2bf(silu_f(w0.w * bf2f(xm.w) + w1.w * bf2f(x0.w) + w2.w * bf2f(xp.w)));
  ((ushort4*)xc)[gid] = o;
}

// ---------------------------------------------------------------------------
// SSM scan: h_t = A h_{t-1} + U_t (64-dim), U given as 4 split-K partials
// (stride PS elems). Overlapping chunks: 32 warm-up steps from h=0 then 32
// emitted (||A^32|| ~ 2e-13 -> exact at fp32).
// ---------------------------------------------------------------------------
__global__ __launch_bounds__(64)
void ssm_scan(const float* __restrict__ Amat, const float* __restrict__ U,
              u16* __restrict__ H, int S, size_t PS)
{
  const int b = blockIdx.y;
  const int c = blockIdx.x;
  const int j = threadIdx.x;
  const int s0 = c * 32;
  const int tstart = (s0 >= 32) ? (s0 - 32) : 0;
  float4 Ar[16];
#pragma unroll
  for (int q = 0; q < 16; ++q) Ar[q] = ((const float4*)(Amat + j * 64))[q];
  __shared__ float hb[64];
  float h = 0.f;
  const float* Ub = U + (size_t)b * S * 64;
  u16* Hb = H + (size_t)b * S * 64;
  for (int t = tstart; t < s0 + 32; ++t) {
    hb[j] = h;
    __syncthreads();
    const size_t idx = (size_t)t * 64 + j;
    float acc0 = Ub[idx] + Ub[PS + idx] + Ub[2 * PS + idx] + Ub[3 * PS + idx];
#pragma unroll
    for (int q = 0; q < 16; ++q) {
      const float4 hv = *(const float4*)&hb[q * 4];
      acc0 += Ar[q].x * hv.x + Ar[q].y * hv.y + Ar[q].z * hv.z + Ar[q].w * hv.w;
    }
    __syncthreads();
    h = acc0;
    if (t >= s0) Hb[idx] = f2bf(h);
  }
}

// ---------------------------------------------------------------------------
// Combined fp32 -> bf16 weight convert: 7 source segments into one contiguous
// dst region (single launch replaces 7).
// ---------------------------------------------------------------------------
struct CvtArgs {
  const float* src[7];
  unsigned beg4[8];   // segment boundaries in float4 units
};

__global__ __launch_bounds__(256)
void cvt_all(CvtArgs a, u16* __restrict__ dst)
{
  const unsigned i = blockIdx.x * 256 + threadIdx.x;
  if (i >= a.beg4[7]) return;
  int s = 0;
#pragma unroll
  for (int k = 1; k < 7; ++k) if (i >= a.beg4[k]) s = k;
  const float4 v = ((const float4*)a.src[s])[i - a.beg4[s]];
  ushort4 o;
  o.x = f2bf(v.x); o.y = f2bf(v.y); o.z = f2bf(v.z); o.w = f2bf(v.w);
  ((ushort4*)dst)[i] = o;
}

// conv_w [D,1,3] -> cwT [3][D] fp32
__global__ __launch_bounds__(256)
void cvt_convw(const float* __restrict__ cw, float* __restrict__ cwT)
{
  const int d = blockIdx.x * 256 + threadIdx.x;
  if (d < 1024) {
    cwT[d]        = cw[d * 3 + 0];
    cwT[1024 + d] = cw[d * 3 + 1];
    cwT[2048 + d] = cw[d * 3 + 2];
  }
}

extern "C" void kernel_launch(void* const* d_in, const int* in_sizes, int n_in,
                              void* d_out, int out_size, void* d_ws, size_t ws_size,
                              hipStream_t stream)
{
  (void)in_sizes; (void)n_in; (void)out_size; (void)ws_size;
  const float* x     = (const float*)d_in[0];
  const float* w1_w  = (const float*)d_in[1];
  const float* w1_b  = (const float*)d_in[2];
  const float* v1_w  = (const float*)d_in[3];
  const float* v1_b  = (const float*)d_in[4];
  const float* w2_w  = (const float*)d_in[5];
  const float* w2_b  = (const float*)d_in[6];
  const float* convw = (const float*)d_in[7];
  const float* Amat  = (const float*)d_in[8];
  const float* Bm    = (const float*)d_in[9];
  const float* Cm    = (const float*)d_in[10];
  const float* ln1_g = (const float*)d_in[11];
  const float* ln1_b = (const float*)d_in[12];
  const float* ln2_g = (const float*)d_in[13];
  const float* ln2_b = (const float*)d_in[14];
  const float* ff1_w = (const float*)d_in[15];
  const float* ff1_b = (const float*)d_in[16];
  const float* ff2_w = (const float*)d_in[17];
  const float* ff2_b = (const float*)d_in[18];

  const int S = 2048, D = 1024, Dff = 2048, NS = 64, BATCH = 4;
  const int NT = BATCH * S; // 8192 tokens

  char* ws = (char*)d_ws;
  size_t off = 0;
  auto alc = [&](size_t bytes) -> void* {
    void* p = ws + off; off += (bytes + 255) & ~(size_t)255; return p;
  };
  u16*   wb1  = (u16*)alc((size_t)D * D * 2);   // w1 || v1 contiguous -> [2048,1024]
  u16*   wv1  = (u16*)alc((size_t)D * D * 2);
  u16*   ww2  = (u16*)alc((size_t)D * D * 2);
  u16*   wf1  = (u16*)alc((size_t)Dff * D * 2);
  u16*   wf2  = (u16*)alc((size_t)D * Dff * 2);
  u16*   wBm  = (u16*)alc((size_t)NS * D * 2);
  u16*   wCm  = (u16*)alc((size_t)D * NS * 2);
  float* cwT  = (float*)alc((size_t)3 * D * 4);
  u16*   h1g  = (u16*)alc((size_t)NT * D * 2);   // h1 (ln1 out), later g
  u16*   vbuf = (u16*)alc((size_t)NT * D * 2);   // v = silu(h@v1^T)
  float* Xb   = (float*)alc((size_t)NT * D * 4); // x1 (bf16 alias), later x2 f32
  u16*   xch2 = (u16*)alc((size_t)NT * D * 2);   // xc, later h2
  float* Ubuf = (float*)alc((size_t)4 * NT * NS * 4); // 4 split-K partials
  u16*   Hbuf = (u16*)alc((size_t)NT * NS * 2);
  u16*   f1b  = (u16*)alc((size_t)NT * Dff * 2);
  u16*   x1b  = (u16*)Xb;                        // x1 bf16 aliases Xb (dead before x2)

  const dim3 blk(256);

  // single combined weight conversion (dst = contiguous wb1..wCm region)
  {
    CvtArgs a;
    const unsigned q = (unsigned)(D * D / 4);      // 262144
    const unsigned qf = (unsigned)(Dff * D / 4);   // 524288
    const unsigned qs = (unsigned)(NS * D / 4);    // 16384
    a.src[0] = w1_w;  a.src[1] = v1_w;  a.src[2] = w2_w;
    a.src[3] = ff1_w; a.src[4] = ff2_w; a.src[5] = Bm; a.src[6] = Cm;
    a.beg4[0] = 0;
    a.beg4[1] = q;          a.beg4[2] = 2 * q;      a.beg4[3] = 3 * q;
    a.beg4[4] = 3 * q + qf; a.beg4[5] = 3 * q + 2 * qf;
    a.beg4[6] = 3 * q + 2 * qf + qs;
    a.beg4[7] = 3 * q + 2 * qf + 2 * qs;
    hipLaunchKernelGGL(cvt_all, dim3((a.beg4[7] + 255) / 256), blk, 0, stream, a, wb1);
  }
  hipLaunchKernelGGL(cvt_convw, dim3(4), blk, 0, stream, convw, cwT);

  // h1 = LN1(x)
  hipLaunchKernelGGL(ln_bf16, dim3(NT), blk, 0, stream, x, ln1_g, ln1_b, h1g);
  // fused: x1 = h1@w1^T + b1 (bf16 -> x1b) ; v = silu(h1@v1^T + b) (bf16 -> vbuf)
  hipLaunchKernelGGL((gemm128<5>), dim3((NT / 128) * (2 * D / 128)), blk, 0, stream,
                     h1g, wb1, w1_b, v1_b, (const float*)nullptr,
                     (void*)x1b, (void*)vbuf, NT, 2 * D, D);
  // xc = silu(dwconv(x1))  (bf16)
  hipLaunchKernelGGL(conv_silu, dim3(NT), blk, 0, stream, x1b, cwT, xch2, S);
  // U partials = xc @ Bm^T  (fp32, N=64, split-K=4 -> grid (1,64,4))
  hipLaunchKernelGGL((gemm_bt<0>), dim3(1, NT / 128, 4), blk, 0, stream,
                     xch2, wBm, (const float*)nullptr, (const u16*)nullptr,
                     (void*)Ubuf, NT, NS, D / 4, D);
  // H = scan(A, sum of U partials)  (bf16)
  hipLaunchKernelGGL(ssm_scan, dim3(S / 32, BATCH), dim3(64), 0, stream,
                     Amat, Ubuf, Hbuf, S, (size_t)NT * NS);
  // g = (H @ Cm^T) * v  (bf16) -> reuse h1 region
  hipLaunchKernelGGL((gemm_bt<2>), dim3(D / 128, NT / 128, 1), blk, 0, stream,
                     Hbuf, wCm, (const float*)nullptr, vbuf,
                     (void*)h1g, NT, D, NS, NS);
  // x2 = g @ w2^T + b2 + x  (fp32 -> Xb)
  hipLaunchKernelGGL((gemm128<3>), dim3((NT / 128) * (D / 128)), blk, 0, stream,
                     h1g, ww2, w2_b, (const float*)nullptr, x,
                     (void*)Xb, (void*)nullptr, NT, D, D);
  // h2 = LN2(x2)  (bf16) -> reuse xc region
  hipLaunchKernelGGL(ln_bf16, dim3(NT), blk, 0, stream, Xb, ln2_g, ln2_b, xch2);
  // f1 = gelu(h2 @ ff1^T + b)  (bf16)
  hipLaunchKernelGGL((gemm128<4>), dim3((NT / 128) * (Dff / 128)), blk, 0, stream,
                     xch2, wf1, ff1_b, (const float*)nullptr, (const float*)nullptr,
                     (void*)f1b, (void*)nullptr, NT, Dff, D);
  // out = f1 @ ff2^T + b + x2  (fp32)
  hipLaunchKernelGGL((gemm128<3>), dim3((NT / 128) * (D / 128)), blk, 0, stream,
                     f1b, wf2, ff2_b, (const float*)nullptr, Xb,
                     d_out, (void*)nullptr, NT, D, Dff);
}

// Round 9
// 261.571 us; speedup vs baseline: 4.8383x; 1.1105x over previous
//
#include <hip/hip_runtime.h>
#include <hip/hip_bf16.h>

typedef unsigned short u16;
typedef __bf16 bf16x8 __attribute__((ext_vector_type(8)));
typedef float f32x4 __attribute__((ext_vector_type(4)));

#define DEV __device__ __forceinline__

DEV u16 f2bf(float f) {
  __hip_bfloat16 h = __float2bfloat16(f);
  union { __hip_bfloat16 h; u16 u; } c; c.h = h; return c.u;
}
DEV float bf2f(u16 u) {
  unsigned int x = ((unsigned int)u) << 16; float f;
  __builtin_memcpy(&f, &x, 4); return f;
}
DEV float silu_f(float x) { return x / (1.f + __expf(-x)); }
DEV float gelu_f(float x) { return 0.5f * x * (1.f + erff(x * 0.70710678118654752f)); }

DEV void gl_lds16(const void* g, void* l) {
  __builtin_amdgcn_global_load_lds(
      (const __attribute__((address_space(1))) void*)g,
      (__attribute__((address_space(3))) void*)l, 16, 0, 0);
}

// ---------------------------------------------------------------------------
// 128x128 bf16 GEMM, BK=64, 4 waves (2x2 of 64x64), single-buffered 32KB LDS.
// __launch_bounds__(256,4): 128 regs/thread (64 VGPR + 64 AGPR acc) -> no
// spill, 4 blocks/CU (R8-verified: 52us fused, MfmaUtil 26.6, conflicts 0).
// DO NOT raise blocks/CU (R6/R7: tighter caps spill acc -> 210-918MB scratch
// writes). T2 XOR swizzle, T1 bijective XCD swizzle, x-major row-band order.
// EPI: 3 = +bias +res(f32) -> f32 out
//      4 = gelu(+bias) -> bf16 out
//      5 = dual: col<1024 -> bf16 (+bias) to outp ; col>=1024 -> bf16
//          silu(+bias2) to outp2 (both ld 1024)
// Requires: M%128==0, N%128==0, K%64==0, grid%8==0.
// ---------------------------------------------------------------------------
template<int EPI>
__global__ __launch_bounds__(256, 4)
void gemm128(const u16* __restrict__ A, const u16* __restrict__ Bw,
             const float* __restrict__ bias, const float* __restrict__ bias2,
             const float* __restrict__ resp,
             void* __restrict__ outp, void* __restrict__ outp2,
             int M, int N, int K)
{
  __shared__ alignas(16) u16 As[128 * 64];
  __shared__ alignas(16) u16 Bs[128 * 64];

  const int t = threadIdx.x;
  const int w = t >> 6, l = t & 63;
  const int wm = w >> 1, wn = w & 1;
  const int lr = l & 15, lq = l >> 4;
  const int ir = l >> 3, ik = l & 7;
  const int kkl = ik ^ ir;             // T2 pre-swizzled global k-chunk

  // T1: bijective chunked XCD swizzle, x-major tile order (row-band per XCD)
  const int nwg = gridDim.x;
  int lin = blockIdx.x;
  lin = (lin & 7) * (nwg >> 3) + (lin >> 3);
  const int nbx = N >> 7;
  const int by = lin / nbx, bx = lin - by * nbx;
  const int brow = by << 7, bcol = bx << 7;

  // staging: wave w, sub s covers rows s*32 + w*8 + ir, chunk kkl (16B)
  const u16* gA = A + (size_t)(brow + w * 8 + ir) * K + kkl * 8;
  const u16* gB = Bw + (size_t)(bcol + w * 8 + ir) * K + kkl * 8;

  f32x4 acc[4][4] = {};
  const int nt = K >> 6;

  for (int kt = 0; kt < nt; ++kt) {
#pragma unroll
    for (int s = 0; s < 4; ++s) {
      gl_lds16(gA + (size_t)(s * 32) * K, &As[(s * 32 + w * 8) * 64]);
      gl_lds16(gB + (size_t)(s * 32) * K, &Bs[(s * 32 + w * 8) * 64]);
    }
    gA += 64; gB += 64;
    __syncthreads();                   // drain vm+lgkm, barrier
#pragma unroll
    for (int ks = 0; ks < 2; ++ks) {
      bf16x8 af[4], bf[4];
#pragma unroll
      for (int mi = 0; mi < 4; ++mi) {
        const int ro = wm * 64 + mi * 16 + lr;
        const int ck = (ks * 4 + lq) ^ (ro & 7);
        af[mi] = *(const bf16x8*)&As[ro * 64 + ck * 8];
      }
#pragma unroll
      for (int ni = 0; ni < 4; ++ni) {
        const int ro = wn * 64 + ni * 16 + lr;
        const int ck = (ks * 4 + lq) ^ (ro & 7);
        bf[ni] = *(const bf16x8*)&Bs[ro * 64 + ck * 8];
      }
#pragma unroll
      for (int mi = 0; mi < 4; ++mi)
#pragma unroll
        for (int ni = 0; ni < 4; ++ni)
          acc[mi][ni] = __builtin_amdgcn_mfma_f32_16x16x32_bf16(af[mi], bf[ni], acc[mi][ni], 0, 0, 0);
    }
    __syncthreads();                   // reads done before next overwrite
  }

  // epilogue: row = brow + wm*64 + mi*16 + lq*4 + r ; col = bcol + wn*64 + ni*16 + lr
#pragma unroll
  for (int ni = 0; ni < 4; ++ni) {
    const int col = bcol + wn * 64 + ni * 16 + lr;
    float bv = 0.f;
    if (EPI == 3 || EPI == 4) bv = bias[col];
    if (EPI == 5) bv = (col < 1024) ? bias[col] : bias2[col - 1024];
#pragma unroll
    for (int mi = 0; mi < 4; ++mi) {
      const int row0 = brow + wm * 64 + mi * 16 + lq * 4;
#pragma unroll
      for (int r = 0; r < 4; ++r) {
        const int row = row0 + r;
        const float raw = acc[mi][ni][r];
        if (EPI == 3) {
          const size_t idx = (size_t)row * N + col;
          ((float*)outp)[idx] = raw + bv + resp[idx];
        } else if (EPI == 4) {
          ((u16*)outp)[(size_t)row * N + col] = f2bf(gelu_f(raw + bv));
        } else {
          if (col < 1024) ((u16*)outp)[(size_t)row * 1024 + col] = f2bf(raw + bv);
          else ((u16*)outp2)[(size_t)row * 1024 + (col - 1024)] = f2bf(silu_f(raw + bv));
        }
      }
    }
  }
}

// ---------------------------------------------------------------------------
// Small-shape bf16 GEMM. 128x128 tile, BK=32, 4 waves, 2-phase dbuf.
// Kst = row stride of A/B (elements); K = k-length iterated by THIS block.
// blockIdx.z = split-K part (A,B offset by part*K; outp by part*M*N).
// EPI: 0 = +bias -> f32 ; 2 = (*mul) -> bf16.
// ---------------------------------------------------------------------------
template<int EPI>
__global__ __launch_bounds__(256)
void gemm_bt(const u16* __restrict__ A, const u16* __restrict__ Bw,
             const float* __restrict__ bias, const u16* __restrict__ mulp,
             void* __restrict__ outp, int M, int N, int K, int Kst)
{
  __shared__ u16 As[2][128 * 32];
  __shared__ u16 Bs[2][128 * 32];
  const int t = threadIdx.x;
  const int w = t >> 6, l = t & 63;
  const int wr = w >> 1, wc = w & 1;
  const int brow = blockIdx.y << 7;
  const int bcol = blockIdx.x << 7;
  const int part = blockIdx.z;
  A += (size_t)part * K;
  Bw += (size_t)part * K;
  float* outf = (float*)outp + (size_t)part * M * N;

  const u16* gA0 = A + (size_t)(brow + (t >> 2)) * Kst + ((t & 3) << 3);
  const u16* gA1 = gA0 + (size_t)64 * Kst;
  int bn0 = bcol + (t >> 2);      if (bn0 > N - 1) bn0 = N - 1;
  int bn1 = bcol + 64 + (t >> 2); if (bn1 > N - 1) bn1 = N - 1;
  const u16* gB0 = Bw + (size_t)bn0 * Kst + ((t & 3) << 3);
  const u16* gB1 = Bw + (size_t)bn1 * Kst + ((t & 3) << 3);
  const int woff = w << 9;

  auto stage = [&](int b) {
    gl_lds16(gA0, &As[b][woff]);        gl_lds16(gA1, &As[b][2048 + woff]);
    gl_lds16(gB0, &Bs[b][woff]);        gl_lds16(gB1, &Bs[b][2048 + woff]);
    gA0 += 32; gA1 += 32; gB0 += 32; gB1 += 32;
  };

  f32x4 acc[4][4] = {};
  const int lr = l & 15, lk = (l >> 4) << 3;
  const int nt = K >> 5;

  stage(0);
  __syncthreads();
  int cur = 0;
  for (int kt = 0; kt < nt; ++kt) {
    if (kt + 1 < nt) stage(cur ^ 1);
    bf16x8 af[4], bfr[4];
#pragma unroll
    for (int i = 0; i < 4; ++i)
      af[i] = *(const bf16x8*)&As[cur][(wr * 64 + i * 16 + lr) * 32 + lk];
#pragma unroll
    for (int j = 0; j < 4; ++j)
      bfr[j] = *(const bf16x8*)&Bs[cur][(wc * 64 + j * 16 + lr) * 32 + lk];
#pragma unroll
    for (int i = 0; i < 4; ++i)
#pragma unroll
      for (int j = 0; j < 4; ++j)
        acc[i][j] = __builtin_amdgcn_mfma_f32_16x16x32_bf16(af[i], bfr[j], acc[i][j], 0, 0, 0);
    __syncthreads();
    cur ^= 1;
  }

  const int lq = l >> 4;
#pragma unroll
  for (int j = 0; j < 4; ++j) {
    const int col = bcol + wc * 64 + j * 16 + lr;
    if (col >= N) continue;
    const float bv = (EPI == 0 && bias) ? bias[col] : 0.f;
#pragma unroll
    for (int i = 0; i < 4; ++i) {
      const int row0 = brow + wr * 64 + i * 16 + lq * 4;
#pragma unroll
      for (int r = 0; r < 4; ++r) {
        const size_t idx = (size_t)(row0 + r) * N + col;
        const float raw = acc[i][j][r];
        if (EPI == 0) outf[idx] = raw + bv;
        else          ((u16*)outp)[idx] = f2bf(raw * bf2f(mulp[idx]));
      }
    }
  }
}

// ---------------------------------------------------------------------------
// LayerNorm over last dim (1024), fp32 in -> bf16 out. ONE WAVE PER ROW
// (4 rows/block): lane reads 4x float4, pure shfl_xor reduce -- no LDS, no
// block barrier. Grid = rows/4.
// ---------------------------------------------------------------------------
__global__ __launch_bounds__(256)
void ln_bf16(const float* __restrict__ x, const float* __restrict__ g,
             const float* __restrict__ b, u16* __restrict__ out)
{
  const int w = threadIdx.x >> 6, l = threadIdx.x & 63;
  const int row = blockIdx.x * 4 + w;
  const float4* xr = (const float4*)(x + (size_t)row * 1024);
  float4 v[4];
  float s = 0.f, sq = 0.f;
#pragma unroll
  for (int c = 0; c < 4; ++c) {
    v[c] = xr[c * 64 + l];
    s += v[c].x + v[c].y + v[c].z + v[c].w;
    sq += v[c].x * v[c].x + v[c].y * v[c].y + v[c].z * v[c].z + v[c].w * v[c].w;
  }
#pragma unroll
  for (int o = 32; o; o >>= 1) { s += __shfl_xor(s, o); sq += __shfl_xor(sq, o); }
  const float mean = s * (1.f / 1024.f);
  const float var = sq * (1.f / 1024.f) - mean * mean;
  const float rs = rsqrtf(var + 1e-5f);
  ushort4* orow = (ushort4*)(out + (size_t)row * 1024);
#pragma unroll
  for (int c = 0; c < 4; ++c) {
    const float4 gg = ((const float4*)g)[c * 64 + l];
    const float4 bb = ((const float4*)b)[c * 64 + l];
    ushort4 o;
    o.x = f2bf((v[c].x - mean) * rs * gg.x + bb.x);
    o.y = f2bf((v[c].y - mean) * rs * gg.y + bb.y);
    o.z = f2bf((v[c].z - mean) * rs * gg.z + bb.z);
    o.w = f2bf((v[c].w - mean) * rs * gg.w + bb.w);
    orow[c * 64 + l] = o;
  }
}

// ---------------------------------------------------------------------------
// Depthwise conv1d (k=3, pad=1) + SiLU. x1 bf16 [B,S,D] -> xc bf16.
// 4 gid-units per block (grid = NT/4).
// ---------------------------------------------------------------------------
__global__ __launch_bounds__(256)
void conv_silu(const u16* __restrict__ x1, const float* __restrict__ cwT,
               u16* __restrict__ xc, int S)
{
#pragma unroll
  for (int kk = 0; kk < 4; ++kk) {
    const size_t gid = (size_t)blockIdx.x * 1024 + kk * 256 + threadIdx.x;
    const int dq = (int)(gid & 255);
    const size_t tok = gid >> 8;
    const int s = (int)(tok % (size_t)S);
    ushort4 zz; zz.x = 0; zz.y = 0; zz.z = 0; zz.w = 0;
    const ushort4* base = (const ushort4*)x1 + tok * 256;
    const ushort4 xm = (s > 0) ? base[dq - 256] : zz;
    const ushort4 x0 = base[dq];
    const ushort4 xp = (s < S - 1) ? base[dq + 256] : zz;
    const float4 w0 = ((const float4*)cwT)[dq];
    const float4 w1 = ((const float4*)(cwT + 1024))[dq];
    const float4 w2 = ((const float4*)(cwT + 2048))[dq];
    ushort4 o;
    o.x = f2bf(silu_f(w0.x * bf2f(xm.x) + w1.x * bf2f(x0.x) + w2.x * bf2f(xp.x)));
    o.y = f2bf(silu_f(w0.y * bf2f(xm.y) + w1.y * bf2f(x0.y) + w2.y * bf2f(xp.y)));
    o.z = f2bf(silu_f(w0.z * bf2f(xm.z) + w1.z * bf2f(x0.z) + w2.z * bf2f(xp.z)));
    o.w = f2bf(silu_f(w0.w * bf2f(xm.w) + w1.w * bf2f(x0.w) + w2.w * bf2f(xp.w)));
    ((ushort4*)xc)[gid] = o;
  }
}

// ---------------------------------------------------------------------------
// SSM scan: h_t = A h_{t-1} + U_t (64-dim), U given as 4 split-K partials
// (stride PS elems). Overlapping chunks of 16: 16 warm-up steps from h=0
// then 16 emitted (||A^16|| ~ 4e-7, spectral radius ~0.4 -> error ~1e-6,
// far under bf16 output rounding). Grid = (S/16, BATCH), 1 wave/block.
// ---------------------------------------------------------------------------
__global__ __launch_bounds__(64)
void ssm_scan(const float* __restrict__ Amat, const float* __restrict__ U,
              u16* __restrict__ H, int S, size_t PS)
{
  const int b = blockIdx.y;
  const int c = blockIdx.x;
  const int j = threadIdx.x;
  const int s0 = c * 16;
  const int tstart = (s0 >= 16) ? (s0 - 16) : 0;
  float4 Ar[16];
#pragma unroll
  for (int q = 0; q < 16; ++q) Ar[q] = ((const float4*)(Amat + j * 64))[q];
  __shared__ float hb[64];
  float h = 0.f;
  const float* Ub = U + (size_t)b * S * 64;
  u16* Hb = H + (size_t)b * S * 64;
  for (int t = tstart; t < s0 + 16; ++t) {
    hb[j] = h;
    __syncthreads();
    const size_t idx = (size_t)t * 64 + j;
    float acc0 = Ub[idx] + Ub[PS + idx] + Ub[2 * PS + idx] + Ub[3 * PS + idx];
#pragma unroll
    for (int q = 0; q < 16; ++q) {
      const float4 hv = *(const float4*)&hb[q * 4];
      acc0 += Ar[q].x * hv.x + Ar[q].y * hv.y + Ar[q].z * hv.z + Ar[q].w * hv.w;
    }
    __syncthreads();
    h = acc0;
    if (t >= s0) Hb[idx] = f2bf(h);
  }
}

// ---------------------------------------------------------------------------
// Combined weight prep: fp32->bf16 for 7 segments into one contiguous dst,
// PLUS conv_w [D,1,3] -> cwT [3][D] fp32 transpose (tail index range).
// Single launch replaces 8.
// ---------------------------------------------------------------------------
struct CvtArgs {
  const float* src[7];
  const float* convw;
  float* cwT;
  unsigned beg4[8];   // segment boundaries in float4 units
};

__global__ __launch_bounds__(256)
void cvt_all(CvtArgs a, u16* __restrict__ dst)
{
  const unsigned i = blockIdx.x * 256 + threadIdx.x;
  if (i < a.beg4[7]) {
    int s = 0;
#pragma unroll
    for (int k = 1; k < 7; ++k) if (i >= a.beg4[k]) s = k;
    const float4 v = ((const float4*)a.src[s])[i - a.beg4[s]];
    ushort4 o;
    o.x = f2bf(v.x); o.y = f2bf(v.y); o.z = f2bf(v.z); o.w = f2bf(v.w);
    ((ushort4*)dst)[i] = o;
  } else {
    const unsigned j = i - a.beg4[7];  // 0 .. 3071 over 768 extra float4 slots
    if (j < 3072 / 4) {
#pragma unroll
      for (int e = 0; e < 4; ++e) {
        const unsigned gi = j * 4 + e;        // index into conv_w flat [1024*3]
        const unsigned d = gi / 3, r = gi % 3;
        a.cwT[r * 1024 + d] = a.convw[gi];
      }
    }
  }
}

extern "C" void kernel_launch(void* const* d_in, const int* in_sizes, int n_in,
                              void* d_out, int out_size, void* d_ws, size_t ws_size,
                              hipStream_t stream)
{
  (void)in_sizes; (void)n_in; (void)out_size; (void)ws_size;
  const float* x     = (const float*)d_in[0];
  const float* w1_w  = (const float*)d_in[1];
  const float* w1_b  = (const float*)d_in[2];
  const float* v1_w  = (const float*)d_in[3];
  const float* v1_b  = (const float*)d_in[4];
  const float* w2_w  = (const float*)d_in[5];
  const float* w2_b  = (const float*)d_in[6];
  const float* convw = (const float*)d_in[7];
  const float* Amat  = (const float*)d_in[8];
  const float* Bm    = (const float*)d_in[9];
  const float* Cm    = (const float*)d_in[10];
  const float* ln1_g = (const float*)d_in[11];
  const float* ln1_b = (const float*)d_in[12];
  const float* ln2_g = (const float*)d_in[13];
  const float* ln2_b = (const float*)d_in[14];
  const float* ff1_w = (const float*)d_in[15];
  const float* ff1_b = (const float*)d_in[16];
  const float* ff2_w = (const float*)d_in[17];
  const float* ff2_b = (const float*)d_in[18];

  const int S = 2048, D = 1024, Dff = 2048, NS = 64, BATCH = 4;
  const int NT = BATCH * S; // 8192 tokens

  char* ws = (char*)d_ws;
  size_t off = 0;
  auto alc = [&](size_t bytes) -> void* {
    void* p = ws + off; off += (bytes + 255) & ~(size_t)255; return p;
  };
  u16*   wb1  = (u16*)alc((size_t)D * D * 2);   // w1 || v1 contiguous -> [2048,1024]
  u16*   wv1  = (u16*)alc((size_t)D * D * 2);
  u16*   ww2  = (u16*)alc((size_t)D * D * 2);
  u16*   wf1  = (u16*)alc((size_t)Dff * D * 2);
  u16*   wf2  = (u16*)alc((size_t)D * Dff * 2);
  u16*   wBm  = (u16*)alc((size_t)NS * D * 2);
  u16*   wCm  = (u16*)alc((size_t)D * NS * 2);
  float* cwT  = (float*)alc((size_t)3 * D * 4);
  u16*   h1g  = (u16*)alc((size_t)NT * D * 2);   // h1 (ln1 out), later g
  u16*   vbuf = (u16*)alc((size_t)NT * D * 2);   // v = silu(h@v1^T)
  float* Xb   = (float*)alc((size_t)NT * D * 4); // x1 (bf16 alias), later x2 f32
  u16*   xch2 = (u16*)alc((size_t)NT * D * 2);   // xc, later h2
  float* Ubuf = (float*)alc((size_t)4 * NT * NS * 4); // 4 split-K partials
  u16*   Hbuf = (u16*)alc((size_t)NT * NS * 2);
  u16*   f1b  = (u16*)alc((size_t)NT * Dff * 2);
  u16*   x1b  = (u16*)Xb;                        // x1 bf16 aliases Xb (dead before x2)

  const dim3 blk(256);

  // single combined weight conversion + conv_w transpose
  {
    CvtArgs a;
    const unsigned q = (unsigned)(D * D / 4);      // 262144
    const unsigned qf = (unsigned)(Dff * D / 4);   // 524288
    const unsigned qs = (unsigned)(NS * D / 4);    // 16384
    a.src[0] = w1_w;  a.src[1] = v1_w;  a.src[2] = w2_w;
    a.src[3] = ff1_w; a.src[4] = ff2_w; a.src[5] = Bm; a.src[6] = Cm;
    a.convw = convw; a.cwT = cwT;
    a.beg4[0] = 0;
    a.beg4[1] = q;          a.beg4[2] = 2 * q;      a.beg4[3] = 3 * q;
    a.beg4[4] = 3 * q + qf; a.beg4[5] = 3 * q + 2 * qf;
    a.beg4[6] = 3 * q + 2 * qf + qs;
    a.beg4[7] = 3 * q + 2 * qf + 2 * qs;
    const unsigned total = a.beg4[7] + 3072 / 4;
    hipLaunchKernelGGL(cvt_all, dim3((total + 255) / 256), blk, 0, stream, a, wb1);
  }

  // h1 = LN1(x)   (one wave per row)
  hipLaunchKernelGGL(ln_bf16, dim3(NT / 4), blk, 0, stream, x, ln1_g, ln1_b, h1g);
  // fused: x1 = h1@w1^T + b1 (bf16 -> x1b) ; v = silu(h1@v1^T + b) (bf16 -> vbuf)
  hipLaunchKernelGGL((gemm128<5>), dim3((NT / 128) * (2 * D / 128)), blk, 0, stream,
                     h1g, wb1, w1_b, v1_b, (const float*)nullptr,
                     (void*)x1b, (void*)vbuf, NT, 2 * D, D);
  // xc = silu(dwconv(x1))  (bf16)
  hipLaunchKernelGGL(conv_silu, dim3(NT / 4), blk, 0, stream, x1b, cwT, xch2, S);
  // U partials = xc @ Bm^T  (fp32, N=64, split-K=4 -> grid (1,64,4))
  hipLaunchKernelGGL((gemm_bt<0>), dim3(1, NT / 128, 4), blk, 0, stream,
                     xch2, wBm, (const float*)nullptr, (const u16*)nullptr,
                     (void*)Ubuf, NT, NS, D / 4, D);
  // H = scan(A, sum of U partials)  (bf16), chunk=16
  hipLaunchKernelGGL(ssm_scan, dim3(S / 16, BATCH), dim3(64), 0, stream,
                     Amat, Ubuf, Hbuf, S, (size_t)NT * NS);
  // g = (H @ Cm^T) * v  (bf16) -> reuse h1 region
  hipLaunchKernelGGL((gemm_bt<2>), dim3(D / 128, NT / 128, 1), blk, 0, stream,
                     Hbuf, wCm, (const float*)nullptr, vbuf,
                     (void*)h1g, NT, D, NS, NS);
  // x2 = g @ w2^T + b2 + x  (fp32 -> Xb)
  hipLaunchKernelGGL((gemm128<3>), dim3((NT / 128) * (D / 128)), blk, 0, stream,
                     h1g, ww2, w2_b, (const float*)nullptr, x,
                     (void*)Xb, (void*)nullptr, NT, D, D);
  // h2 = LN2(x2)  (bf16) -> reuse xc region
  hipLaunchKernelGGL(ln_bf16, dim3(NT / 4), blk, 0, stream, Xb, ln2_g, ln2_b, xch2);
  // f1 = gelu(h2 @ ff1^T + b)  (bf16)
  hipLaunchKernelGGL((gemm128<4>), dim3((NT / 128) * (Dff / 128)), blk, 0, stream,
                     xch2, wf1, ff1_b, (const float*)nullptr, (const float*)nullptr,
                     (void*)f1b, (void*)nullptr, NT, Dff, D);
  // out = f1 @ ff2^T + b + x2  (fp32)
  hipLaunchKernelGGL((gemm128<3>), dim3((NT / 128) * (D / 128)), blk, 0, stream,
                     f1b, wf2, ff2_b, (const float*)nullptr, Xb,
                     d_out, (void*)nullptr, NT, D, Dff);
}

// Round 11
// 249.913 us; speedup vs baseline: 5.0640x; 1.0466x over previous
//
#include <hip/hip_runtime.h>
#include <hip/hip_bf16.h>

typedef unsigned short u16;
typedef __bf16 bf16x8 __attribute__((ext_vector_type(8)));
typedef float f32x4 __attribute__((ext_vector_type(4)));

#define DEV __device__ __forceinline__

DEV u16 f2bf(float f) {
  __hip_bfloat16 h = __float2bfloat16(f);
  union { __hip_bfloat16 h; u16 u; } c; c.h = h; return c.u;
}
DEV float bf2f(u16 u) {
  unsigned int x = ((unsigned int)u) << 16; float f;
  __builtin_memcpy(&f, &x, 4); return f;
}
DEV float silu_f(float x) { return x / (1.f + __expf(-x)); }
// tanh-form GELU: |err| < ~1e-3, below bf16 rounding of the stored result
DEV float gelu_f(float x) {
  const float u = 0.7978845608f * (x + 0.044715f * x * x * x);
  const float t = 1.f - 2.f / (__expf(2.f * u) + 1.f);
  return 0.5f * x * (1.f + t);
}

DEV void gl_lds16(const void* g, void* l) {
  __builtin_amdgcn_global_load_lds(
      (const __attribute__((address_space(1))) void*)g,
      (__attribute__((address_space(3))) void*)l, 16, 0, 0);
}

DEV void vmw6() { asm volatile("s_waitcnt vmcnt(6)" ::: "memory"); }
DEV void vmw0() { asm volatile("s_waitcnt vmcnt(0)" ::: "memory"); }
DEV void lgkm0() { asm volatile("s_waitcnt lgkmcnt(0)" ::: "memory"); }
DEV void BAR() { __builtin_amdgcn_s_barrier(); }

// ---------------------------------------------------------------------------
// gemm8p: 256x256 bf16 GEMM, BK=64, 512 thr = 8 waves (2M x 4N, per-wave
// 128x64). 8-phase counted-vmcnt schedule, 2 K-tiles/iter.
// REGION LIFETIMES (per iter, verified): A-half rows 0-127 of buf0 read at
// ph1(q0,wm=0-rows 0-63) and ph3(q1,wm=0-rows 64-127); A rows 128-255 read
// ph1/ph3 by wm=1. So buf0.A* last read ph3; buf1.A* last read ph7. B last
// read ph1 (buf0) / ph5 (buf1). STAGE SLOTS (all >= last-read+1 barrier):
//   ph1: b1.A1<-2i+1 | ph2: b0.B0<-t2 | ph3: b0.B1<-t2 | ph4: b0.A0<-t2 +vm6
//   ph5: b0.A1<-t2   | ph6: b1.B0<-t3 | ph7: b1.B1<-t3 | ph8: b1.A0<-t3 +vm6
// FIFO ledger: ph4's vmcnt(6) -> oldest-8 = {prev p6,p7,p8, this p1} = buf1
// complete before ph5 reads; ph8's -> oldest-8 = {p2..p5} = buf0(t2) complete
// before next ph1. R10's bug: b0.A0 staged at ph2, racing ph3's read of rows
// 64-127 -- slot order above is the fix (reads/epilogue unchanged).
// T2 XOR swizzle (pre-swizzled global src + swizzled ds_read), T1 XCD
// swizzle, T5 setprio. launch_bounds(512,2): ~222 regs < 256 cap, no spill.
// EPI: 4 = gelu(+bias) -> bf16 ; 5 = dual (col<1024 -> bf16+bias to outp,
// col>=1024 -> bf16 silu(+bias2) to outp2, both ld 1024).
// Requires: M%256==0, N%256==0, K%128==0, K/64>=4, grid%8==0.
// ---------------------------------------------------------------------------
template<int EPI>
__global__ __launch_bounds__(512, 2)
void gemm8p(const u16* __restrict__ A, const u16* __restrict__ Bw,
            const float* __restrict__ bias, const float* __restrict__ bias2,
            void* __restrict__ outp, void* __restrict__ outp2,
            int M, int N, int K)
{
  constexpr int BUFE = 32768;              // elems per buffer (A 16K + B 16K)
  __shared__ alignas(16) u16 lds[2 * BUFE];  // 128 KB

  const int t = threadIdx.x;
  const int w = t >> 6, l = t & 63;
  const int wm = w >> 2, wn = w & 3;       // 2M x 4N
  const int lr = l & 15, lq = l >> 4;
  const int ir = l >> 3, ik = l & 7;
  const int kkl = ik ^ ir;                 // T2 pre-swizzled k-chunk

  // T1 bijective XCD swizzle, x-major (row-band per XCD)
  const int nwg = gridDim.x;
  int lin = blockIdx.x;
  lin = (lin & 7) * (nwg >> 3) + (lin >> 3);
  const int nbx = N >> 8;
  const int by = lin / nbx, bx = lin - by * nbx;
  const int brow = by << 8, bcol = bx << 8;

  const u16* Aw = A + (size_t)(brow + w * 16 + ir) * K + kkl * 8;
  const u16* Bww = Bw + (size_t)(bcol + w * 16 + ir) * K + kkl * 8;

  auto stageA = [&](int buf, int h, int kt) {
#pragma unroll
    for (int ld = 0; ld < 2; ++ld)
      gl_lds16(Aw + (size_t)(h * 128 + ld * 8) * K + kt * 64,
               &lds[buf * BUFE + (h * 128 + w * 16 + ld * 8) * 64]);
  };
  auto stageB = [&](int buf, int h, int kt) {
#pragma unroll
    for (int ld = 0; ld < 2; ++ld)
      gl_lds16(Bww + (size_t)(h * 128 + ld * 8) * K + kt * 64,
               &lds[buf * BUFE + 16384 + (h * 128 + w * 16 + ld * 8) * 64]);
  };

  bf16x8 af[4][2], bf[4][2];
  auto readA = [&](int buf, int h) {          // 8 ds_read_b128
#pragma unroll
    for (int mi = 0; mi < 4; ++mi)
#pragma unroll
      for (int ks = 0; ks < 2; ++ks) {
        const int ro = wm * 128 + (h * 4 + mi) * 16 + lr;
        const int ck = (ks * 4 + lq) ^ (ro & 7);
        af[mi][ks] = *(const bf16x8*)&lds[buf * BUFE + ro * 64 + ck * 8];
      }
  };
  auto readB = [&](int buf) {                 // 8 ds_read_b128
#pragma unroll
    for (int ni = 0; ni < 4; ++ni)
#pragma unroll
      for (int ks = 0; ks < 2; ++ks) {
        const int ro = wn * 64 + ni * 16 + lr;
        const int ck = (ks * 4 + lq) ^ (ro & 7);
        bf[ni][ks] = *(const bf16x8*)&lds[buf * BUFE + 16384 + ro * 64 + ck * 8];
      }
  };

  f32x4 acc[8][4] = {};
#define MFMA_Q(q, nh)                                                        \
  __builtin_amdgcn_s_setprio(1);                                             \
  _Pragma("unroll")                                                          \
  for (int mi = 0; mi < 4; ++mi)                                             \
    _Pragma("unroll")                                                        \
    for (int ni = 0; ni < 2; ++ni)                                           \
      _Pragma("unroll")                                                      \
      for (int ks = 0; ks < 2; ++ks)                                         \
        acc[(q) * 4 + mi][(nh) * 2 + ni] =                                   \
            __builtin_amdgcn_mfma_f32_16x16x32_bf16(                         \
                af[mi][ks], bf[(nh) * 2 + ni][ks],                           \
                acc[(q) * 4 + mi][(nh) * 2 + ni], 0, 0, 0);                  \
  __builtin_amdgcn_s_setprio(0);

#define PH_TAIL() BAR(); lgkm0();
#define PH_END()  BAR();

  const int nt = K >> 6;
  // prologue in steady-state slot order: b0 {B0,B1,A0,A1}, b1 {B0,B1,A0};
  // vmcnt(6) -> b0's 8 landed, b1's 6 in flight (A1 comes at ph1)
  stageB(0, 0, 0); stageB(0, 1, 0); stageA(0, 0, 0); stageA(0, 1, 0);
  stageB(1, 0, 1); stageB(1, 1, 1); stageA(1, 0, 1);
  vmw6();
  BAR();

  for (int i = 0; i < (nt >> 1); ++i) {
    const int tb = 2 * i + 1;                                 // < nt always
    const int t2 = (2 * i + 2 < nt) ? 2 * i + 2 : nt - 1;
    const int t3 = (2 * i + 3 < nt) ? 2 * i + 3 : nt - 1;
    // ph1: read buf0 A-q0 + B; stage b1.A1 <- tile 2i+1 (last read prev ph7)
    readA(0, 0); readB(0); stageA(1, 1, tb);
    PH_TAIL(); MFMA_Q(0, 0); PH_END();
    // ph2: stage b0.B0 <- t2 (B last read ph1)
    stageB(0, 0, t2);
    PH_TAIL(); MFMA_Q(0, 1); PH_END();
    // ph3: read buf0 A-q1; stage b0.B1 <- t2
    readA(0, 1); stageB(0, 1, t2);
    PH_TAIL(); MFMA_Q(1, 0); PH_END();
    // ph4: stage b0.A0 <- t2 (A last read ph3); vmcnt(6) -> buf1 complete
    stageA(0, 0, t2);
    vmw6();
    PH_TAIL(); MFMA_Q(1, 1); PH_END();
    // ph5: read buf1 A-q0 + B; stage b0.A1 <- t2
    readA(1, 0); readB(1); stageA(0, 1, t2);
    PH_TAIL(); MFMA_Q(0, 0); PH_END();
    // ph6: stage b1.B0 <- t3 (b1.B last read ph5)
    stageB(1, 0, t3);
    PH_TAIL(); MFMA_Q(0, 1); PH_END();
    // ph7: read buf1 A-q1; stage b1.B1 <- t3
    readA(1, 1); stageB(1, 1, t3);
    PH_TAIL(); MFMA_Q(1, 0); PH_END();
    // ph8: stage b1.A0 <- t3 (b1.A last read ph7); vmcnt(6) -> buf0(t2) done
    stageA(1, 0, t3);
    vmw6();
    PH_TAIL(); MFMA_Q(1, 1); PH_END();
  }
  vmw0();   // drain remaining LDS-dest loads before epilogue

  // epilogue: row = brow + wm*128 + mi*16 + lq*4 + r ; col = bcol + wn*64 + ni*16 + lr
#pragma unroll
  for (int ni = 0; ni < 4; ++ni) {
    const int col = bcol + wn * 64 + ni * 16 + lr;
    float bv = 0.f;
    if (EPI == 4) bv = bias[col];
    if (EPI == 5) bv = (col < 1024) ? bias[col] : bias2[col - 1024];
#pragma unroll
    for (int mi = 0; mi < 8; ++mi) {
      const int row0 = brow + wm * 128 + mi * 16 + lq * 4;
#pragma unroll
      for (int r = 0; r < 4; ++r) {
        const int row = row0 + r;
        const float raw = acc[mi][ni][r];
        if (EPI == 4) {
          ((u16*)outp)[(size_t)row * N + col] = f2bf(gelu_f(raw + bv));
        } else {
          if (col < 1024) ((u16*)outp)[(size_t)row * 1024 + col] = f2bf(raw + bv);
          else ((u16*)outp2)[(size_t)row * 1024 + (col - 1024)] = f2bf(silu_f(raw + bv));
        }
      }
    }
  }
#undef MFMA_Q
#undef PH_TAIL
#undef PH_END
}

// ---------------------------------------------------------------------------
// 128x128 bf16 GEMM, BK=64, 4 waves, single-buffered 32KB LDS.
// __launch_bounds__(256,4): 128 regs/thread, no spill, 4 blocks/CU
// (R8/R9-verified: ~660 TF effective). T2 swizzle, T1 XCD swizzle.
// EPI: 3 = +bias +res(f32) -> f32 out
// ---------------------------------------------------------------------------
template<int EPI>
__global__ __launch_bounds__(256, 4)
void gemm128(const u16* __restrict__ A, const u16* __restrict__ Bw,
             const float* __restrict__ bias, const float* __restrict__ bias2,
             const float* __restrict__ resp,
             void* __restrict__ outp, void* __restrict__ outp2,
             int M, int N, int K)
{
  __shared__ alignas(16) u16 As[128 * 64];
  __shared__ alignas(16) u16 Bs[128 * 64];

  const int t = threadIdx.x;
  const int w = t >> 6, l = t & 63;
  const int wm = w >> 1, wn = w & 1;
  const int lr = l & 15, lq = l >> 4;
  const int ir = l >> 3, ik = l & 7;
  const int kkl = ik ^ ir;

  const int nwg = gridDim.x;
  int lin = blockIdx.x;
  lin = (lin & 7) * (nwg >> 3) + (lin >> 3);
  const int nbx = N >> 7;
  const int by = lin / nbx, bx = lin - by * nbx;
  const int brow = by << 7, bcol = bx << 7;

  const u16* gA = A + (size_t)(brow + w * 8 + ir) * K + kkl * 8;
  const u16* gB = Bw + (size_t)(bcol + w * 8 + ir) * K + kkl * 8;

  f32x4 acc[4][4] = {};
  const int nt = K >> 6;

  for (int kt = 0; kt < nt; ++kt) {
#pragma unroll
    for (int s = 0; s < 4; ++s) {
      gl_lds16(gA + (size_t)(s * 32) * K, &As[(s * 32 + w * 8) * 64]);
      gl_lds16(gB + (size_t)(s * 32) * K, &Bs[(s * 32 + w * 8) * 64]);
    }
    gA += 64; gB += 64;
    __syncthreads();
#pragma unroll
    for (int ks = 0; ks < 2; ++ks) {
      bf16x8 af[4], bf[4];
#pragma unroll
      for (int mi = 0; mi < 4; ++mi) {
        const int ro = wm * 64 + mi * 16 + lr;
        const int ck = (ks * 4 + lq) ^ (ro & 7);
        af[mi] = *(const bf16x8*)&As[ro * 64 + ck * 8];
      }
#pragma unroll
      for (int ni = 0; ni < 4; ++ni) {
        const int ro = wn * 64 + ni * 16 + lr;
        const int ck = (ks * 4 + lq) ^ (ro & 7);
        bf[ni] = *(const bf16x8*)&Bs[ro * 64 + ck * 8];
      }
#pragma unroll
      for (int mi = 0; mi < 4; ++mi)
#pragma unroll
        for (int ni = 0; ni < 4; ++ni)
          acc[mi][ni] = __builtin_amdgcn_mfma_f32_16x16x32_bf16(af[mi], bf[ni], acc[mi][ni], 0, 0, 0);
    }
    __syncthreads();
  }

#pragma unroll
  for (int ni = 0; ni < 4; ++ni) {
    const int col = bcol + wn * 64 + ni * 16 + lr;
    const float bv = bias[col];
#pragma unroll
    for (int mi = 0; mi < 4; ++mi) {
      const int row0 = brow + wm * 64 + mi * 16 + lq * 4;
#pragma unroll
      for (int r = 0; r < 4; ++r) {
        const int row = row0 + r;
        const size_t idx = (size_t)row * N + col;
        ((float*)outp)[idx] = acc[mi][ni][r] + bv + resp[idx];
      }
    }
  }
}

// ---------------------------------------------------------------------------
// Small-shape bf16 GEMM. 128x128 tile, BK=32, 4 waves, 2-phase dbuf.
// Kst = row stride; blockIdx.z = split-K part.
// EPI: 0 = +bias -> f32 ; 2 = (*mul) -> bf16.
// ---------------------------------------------------------------------------
template<int EPI>
__global__ __launch_bounds__(256)
void gemm_bt(const u16* __restrict__ A, const u16* __restrict__ Bw,
             const float* __restrict__ bias, const u16* __restrict__ mulp,
             void* __restrict__ outp, int M, int N, int K, int Kst)
{
  __shared__ u16 As[2][128 * 32];
  __shared__ u16 Bs[2][128 * 32];
  const int t = threadIdx.x;
  const int w = t >> 6, l = t & 63;
  const int wr = w >> 1, wc = w & 1;
  const int brow = blockIdx.y << 7;
  const int bcol = blockIdx.x << 7;
  const int part = blockIdx.z;
  A += (size_t)part * K;
  Bw += (size_t)part * K;
  float* outf = (float*)outp + (size_t)part * M * N;

  const u16* gA0 = A + (size_t)(brow + (t >> 2)) * Kst + ((t & 3) << 3);
  const u16* gA1 = gA0 + (size_t)64 * Kst;
  int bn0 = bcol + (t >> 2);      if (bn0 > N - 1) bn0 = N - 1;
  int bn1 = bcol + 64 + (t >> 2); if (bn1 > N - 1) bn1 = N - 1;
  const u16* gB0 = Bw + (size_t)bn0 * Kst + ((t & 3) << 3);
  const u16* gB1 = Bw + (size_t)bn1 * Kst + ((t & 3) << 3);
  const int woff = w << 9;

  auto stage = [&](int b) {
    gl_lds16(gA0, &As[b][woff]);        gl_lds16(gA1, &As[b][2048 + woff]);
    gl_lds16(gB0, &Bs[b][woff]);        gl_lds16(gB1, &Bs[b][2048 + woff]);
    gA0 += 32; gA1 += 32; gB0 += 32; gB1 += 32;
  };

  f32x4 acc[4][4] = {};
  const int lr = l & 15, lk = (l >> 4) << 3;
  const int nt = K >> 5;

  stage(0);
  __syncthreads();
  int cur = 0;
  for (int kt = 0; kt < nt; ++kt) {
    if (kt + 1 < nt) stage(cur ^ 1);
    bf16x8 af[4], bfr[4];
#pragma unroll
    for (int i = 0; i < 4; ++i)
      af[i] = *(const bf16x8*)&As[cur][(wr * 64 + i * 16 + lr) * 32 + lk];
#pragma unroll
    for (int j = 0; j < 4; ++j)
      bfr[j] = *(const bf16x8*)&Bs[cur][(wc * 64 + j * 16 + lr) * 32 + lk];
#pragma unroll
    for (int i = 0; i < 4; ++i)
#pragma unroll
      for (int j = 0; j < 4; ++j)
        acc[i][j] = __builtin_amdgcn_mfma_f32_16x16x32_bf16(af[i], bfr[j], acc[i][j], 0, 0, 0);
    __syncthreads();
    cur ^= 1;
  }

  const int lq = l >> 4;
#pragma unroll
  for (int j = 0; j < 4; ++j) {
    const int col = bcol + wc * 64 + j * 16 + lr;
    if (col >= N) continue;
    const float bv = (EPI == 0 && bias) ? bias[col] : 0.f;
#pragma unroll
    for (int i = 0; i < 4; ++i) {
      const int row0 = brow + wr * 64 + i * 16 + lq * 4;
#pragma unroll
      for (int r = 0; r < 4; ++r) {
        const size_t idx = (size_t)(row0 + r) * N + col;
        const float raw = acc[i][j][r];
        if (EPI == 0) outf[idx] = raw + bv;
        else          ((u16*)outp)[idx] = f2bf(raw * bf2f(mulp[idx]));
      }
    }
  }
}

// ---------------------------------------------------------------------------
// LayerNorm over last dim (1024), fp32 in -> bf16 out. One wave per row.
// ---------------------------------------------------------------------------
__global__ __launch_bounds__(256)
void ln_bf16(const float* __restrict__ x, const float* __restrict__ g,
             const float* __restrict__ b, u16* __restrict__ out)
{
  const int w = threadIdx.x >> 6, l = threadIdx.x & 63;
  const int row = blockIdx.x * 4 + w;
  const float4* xr = (const float4*)(x + (size_t)row * 1024);
  float4 v[4];
  float s = 0.f, sq = 0.f;
#pragma unroll
  for (int c = 0; c < 4; ++c) {
    v[c] = xr[c * 64 + l];
    s += v[c].x + v[c].y + v[c].z + v[c].w;
    sq += v[c].x * v[c].x + v[c].y * v[c].y + v[c].z * v[c].z + v[c].w * v[c].w;
  }
#pragma unroll
  for (int o = 32; o; o >>= 1) { s += __shfl_xor(s, o); sq += __shfl_xor(sq, o); }
  const float mean = s * (1.f / 1024.f);
  const float var = sq * (1.f / 1024.f) - mean * mean;
  const float rs = rsqrtf(var + 1e-5f);
  ushort4* orow = (ushort4*)(out + (size_t)row * 1024);
#pragma unroll
  for (int c = 0; c < 4; ++c) {
    const float4 gg = ((const float4*)g)[c * 64 + l];
    const float4 bb = ((const float4*)b)[c * 64 + l];
    ushort4 o;
    o.x = f2bf((v[c].x - mean) * rs * gg.x + bb.x);
    o.y = f2bf((v[c].y - mean) * rs * gg.y + bb.y);
    o.z = f2bf((v[c].z - mean) * rs * gg.z + bb.z);
    o.w = f2bf((v[c].w - mean) * rs * gg.w + bb.w);
    orow[c * 64 + l] = o;
  }
}

// ---------------------------------------------------------------------------
// Depthwise conv1d (k=3, pad=1) + SiLU. x1 bf16 [B,S,D] -> xc bf16.
// ---------------------------------------------------------------------------
__global__ __launch_bounds__(256)
void conv_silu(const u16* __restrict__ x1, const float* __restrict__ cwT,
               u16* __restrict__ xc, int S)
{
#pragma unroll
  for (int kk = 0; kk < 4; ++kk) {
    const size_t gid = (size_t)blockIdx.x * 1024 + kk * 256 + threadIdx.x;
    const int dq = (int)(gid & 255);
    const size_t tok = gid >> 8;
    const int s = (int)(tok % (size_t)S);
    ushort4 zz; zz.x = 0; zz.y = 0; zz.z = 0; zz.w = 0;
    const ushort4* base = (const ushort4*)x1 + tok * 256;
    const ushort4 xm = (s > 0) ? base[dq - 256] : zz;
    const ushort4 x0 = base[dq];
    const ushort4 xp = (s < S - 1) ? base[dq + 256] : zz;
    const float4 w0 = ((const float4*)cwT)[dq];
    const float4 w1 = ((const float4*)(cwT + 1024))[dq];
    const float4 w2 = ((const float4*)(cwT + 2048))[dq];
    ushort4 o;
    o.x = f2bf(silu_f(w0.x * bf2f(xm.x) + w1.x * bf2f(x0.x) + w2.x * bf2f(xp.x)));
    o.y = f2bf(silu_f(w0.y * bf2f(xm.y) + w1.y * bf2f(x0.y) + w2.y * bf2f(xp.y)));
    o.z = f2bf(silu_f(w0.z * bf2f(xm.z) + w1.z * bf2f(x0.z) + w2.z * bf2f(xp.z)));
    o.w = f2bf(silu_f(w0.w * bf2f(xm.w) + w1.w * bf2f(x0.w) + w2.w * bf2f(xp.w)));
    ((ushort4*)xc)[gid] = o;
  }
}

// ---------------------------------------------------------------------------
// SSM scan, chunk=16 warm-up (||A^16|| ~ 4e-7). 4 split-K U partials.
// ---------------------------------------------------------------------------
__global__ __launch_bounds__(64)
void ssm_scan(const float* __restrict__ Amat, const float* __restrict__ U,
              u16* __restrict__ H, int S, size_t PS)
{
  const int b = blockIdx.y;
  const int c = blockIdx.x;
  const int j = threadIdx.x;
  const int s0 = c * 16;
  const int tstart = (s0 >= 16) ? (s0 - 16) : 0;
  float4 Ar[16];
#pragma unroll
  for (int q = 0; q < 16; ++q) Ar[q] = ((const float4*)(Amat + j * 64))[q];
  __shared__ float hb[64];
  float h = 0.f;
  const float* Ub = U + (size_t)b * S * 64;
  u16* Hb = H + (size_t)b * S * 64;
  for (int t = tstart; t < s0 + 16; ++t) {
    hb[j] = h;
    __syncthreads();
    const size_t idx = (size_t)t * 64 + j;
    float acc0 = Ub[idx] + Ub[PS + idx] + Ub[2 * PS + idx] + Ub[3 * PS + idx];
#pragma unroll
    for (int q = 0; q < 16; ++q) {
      const float4 hv = *(const float4*)&hb[q * 4];
      acc0 += Ar[q].x * hv.x + Ar[q].y * hv.y + Ar[q].z * hv.z + Ar[q].w * hv.w;
    }
    __syncthreads();
    h = acc0;
    if (t >= s0) Hb[idx] = f2bf(h);
  }
}

// ---------------------------------------------------------------------------
// Combined weight prep: fp32->bf16 for 7 segments + conv_w transpose.
// ---------------------------------------------------------------------------
struct CvtArgs {
  const float* src[7];
  const float* convw;
  float* cwT;
  unsigned beg4[8];
};

__global__ __launch_bounds__(256)
void cvt_all(CvtArgs a, u16* __restrict__ dst)
{
  const unsigned i = blockIdx.x * 256 + threadIdx.x;
  if (i < a.beg4[7]) {
    int s = 0;
#pragma unroll
    for (int k = 1; k < 7; ++k) if (i >= a.beg4[k]) s = k;
    const float4 v = ((const float4*)a.src[s])[i - a.beg4[s]];
    ushort4 o;
    o.x = f2bf(v.x); o.y = f2bf(v.y); o.z = f2bf(v.z); o.w = f2bf(v.w);
    ((ushort4*)dst)[i] = o;
  } else {
    const unsigned j = i - a.beg4[7];
    if (j < 3072 / 4) {
#pragma unroll
      for (int e = 0; e < 4; ++e) {
        const unsigned gi = j * 4 + e;
        const unsigned d = gi / 3, r = gi % 3;
        a.cwT[r * 1024 + d] = a.convw[gi];
      }
    }
  }
}

extern "C" void kernel_launch(void* const* d_in, const int* in_sizes, int n_in,
                              void* d_out, int out_size, void* d_ws, size_t ws_size,
                              hipStream_t stream)
{
  (void)in_sizes; (void)n_in; (void)out_size; (void)ws_size;
  const float* x     = (const float*)d_in[0];
  const float* w1_w  = (const float*)d_in[1];
  const float* w1_b  = (const float*)d_in[2];
  const float* v1_w  = (const float*)d_in[3];
  const float* v1_b  = (const float*)d_in[4];
  const float* w2_w  = (const float*)d_in[5];
  const float* w2_b  = (const float*)d_in[6];
  const float* convw = (const float*)d_in[7];
  const float* Amat  = (const float*)d_in[8];
  const float* Bm    = (const float*)d_in[9];
  const float* Cm    = (const float*)d_in[10];
  const float* ln1_g = (const float*)d_in[11];
  const float* ln1_b = (const float*)d_in[12];
  const float* ln2_g = (const float*)d_in[13];
  const float* ln2_b = (const float*)d_in[14];
  const float* ff1_w = (const float*)d_in[15];
  const float* ff1_b = (const float*)d_in[16];
  const float* ff2_w = (const float*)d_in[17];
  const float* ff2_b = (const float*)d_in[18];

  const int S = 2048, D = 1024, Dff = 2048, NS = 64, BATCH = 4;
  const int NT = BATCH * S; // 8192 tokens

  char* ws = (char*)d_ws;
  size_t off = 0;
  auto alc = [&](size_t bytes) -> void* {
    void* p = ws + off; off += (bytes + 255) & ~(size_t)255; return p;
  };
  u16*   wb1  = (u16*)alc((size_t)D * D * 2);   // w1 || v1 contiguous
  u16*   wv1  = (u16*)alc((size_t)D * D * 2);
  u16*   ww2  = (u16*)alc((size_t)D * D * 2);
  u16*   wf1  = (u16*)alc((size_t)Dff * D * 2);
  u16*   wf2  = (u16*)alc((size_t)D * Dff * 2);
  u16*   wBm  = (u16*)alc((size_t)NS * D * 2);
  u16*   wCm  = (u16*)alc((size_t)D * NS * 2);
  float* cwT  = (float*)alc((size_t)3 * D * 4);
  u16*   h1g  = (u16*)alc((size_t)NT * D * 2);
  u16*   vbuf = (u16*)alc((size_t)NT * D * 2);
  float* Xb   = (float*)alc((size_t)NT * D * 4);
  u16*   xch2 = (u16*)alc((size_t)NT * D * 2);
  float* Ubuf = (float*)alc((size_t)4 * NT * NS * 4);
  u16*   Hbuf = (u16*)alc((size_t)NT * NS * 2);
  u16*   f1b  = (u16*)alc((size_t)NT * Dff * 2);
  u16*   x1b  = (u16*)Xb;

  const dim3 blk(256);

  {
    CvtArgs a;
    const unsigned q = (unsigned)(D * D / 4);
    const unsigned qf = (unsigned)(Dff * D / 4);
    const unsigned qs = (unsigned)(NS * D / 4);
    a.src[0] = w1_w;  a.src[1] = v1_w;  a.src[2] = w2_w;
    a.src[3] = ff1_w; a.src[4] = ff2_w; a.src[5] = Bm; a.src[6] = Cm;
    a.convw = convw; a.cwT = cwT;
    a.beg4[0] = 0;
    a.beg4[1] = q;          a.beg4[2] = 2 * q;      a.beg4[3] = 3 * q;
    a.beg4[4] = 3 * q + qf; a.beg4[5] = 3 * q + 2 * qf;
    a.beg4[6] = 3 * q + 2 * qf + qs;
    a.beg4[7] = 3 * q + 2 * qf + 2 * qs;
    const unsigned total = a.beg4[7] + 3072 / 4;
    hipLaunchKernelGGL(cvt_all, dim3((total + 255) / 256), blk, 0, stream, a, wb1);
  }

  // h1 = LN1(x)
  hipLaunchKernelGGL(ln_bf16, dim3(NT / 4), blk, 0, stream, x, ln1_g, ln1_b, h1g);
  // fused (8-phase): x1 = h1@w1^T + b1 (bf16) ; v = silu(h1@v1^T + b) (bf16)
  hipLaunchKernelGGL((gemm8p<5>), dim3((NT / 256) * (2 * D / 256)), dim3(512), 0, stream,
                     h1g, wb1, w1_b, v1_b, (void*)x1b, (void*)vbuf, NT, 2 * D, D);
  // xc = silu(dwconv(x1))
  hipLaunchKernelGGL(conv_silu, dim3(NT / 4), blk, 0, stream, x1b, cwT, xch2, S);
  // U partials = xc @ Bm^T  (split-K=4)
  hipLaunchKernelGGL((gemm_bt<0>), dim3(1, NT / 128, 4), blk, 0, stream,
                     xch2, wBm, (const float*)nullptr, (const u16*)nullptr,
                     (void*)Ubuf, NT, NS, D / 4, D);
  // H = scan(A, sum U partials)
  hipLaunchKernelGGL(ssm_scan, dim3(S / 16, BATCH), dim3(64), 0, stream,
                     Amat, Ubuf, Hbuf, S, (size_t)NT * NS);
  // g = (H @ Cm^T) * v
  hipLaunchKernelGGL((gemm_bt<2>), dim3(D / 128, NT / 128, 1), blk, 0, stream,
                     Hbuf, wCm, (const float*)nullptr, vbuf,
                     (void*)h1g, NT, D, NS, NS);
  // x2 = g @ w2^T + b2 + x
  hipLaunchKernelGGL((gemm128<3>), dim3((NT / 128) * (D / 128)), blk, 0, stream,
                     h1g, ww2, w2_b, (const float*)nullptr, x,
                     (void*)Xb, (void*)nullptr, NT, D, D);
  // h2 = LN2(x2)
  hipLaunchKernelGGL(ln_bf16, dim3(NT / 4), blk, 0, stream, Xb, ln2_g, ln2_b, xch2);
  // f1 = gelu(h2 @ ff1^T + b)  (8-phase)
  hipLaunchKernelGGL((gemm8p<4>), dim3((NT / 256) * (Dff / 256)), dim3(512), 0, stream,
                     xch2, wf1, ff1_b, (const float*)nullptr,
                     (void*)f1b, (void*)nullptr, NT, Dff, D);
  // out = f1 @ ff2^T + b + x2
  hipLaunchKernelGGL((gemm128<3>), dim3((NT / 128) * (D / 128)), blk, 0, stream,
                     f1b, wf2, ff2_b, (const float*)nullptr, Xb,
                     d_out, (void*)nullptr, NT, D, Dff);
}